// Round 5
// baseline (330.626 us; speedup 1.0000x reference)
//
#include <hip/hip_runtime.h>
#include <hip/hip_bf16.h>
#include <math.h>

using bf16 = __hip_bfloat16;
typedef short bf16x8 __attribute__((ext_vector_type(8)));
typedef float f32x4  __attribute__((ext_vector_type(4)));

#define DMODEL 1024
#define DSTATE 16
#define DCONV  4
#define DINNER 2048
#define DTRANK 64
#define BSZ    2
#define LSEQ   2048
#define MROWS  (BSZ*LSEQ)   // 4096

#define NCHUNK 32
#define CHUNK  (LSEQ / NCHUNK)     // 64
#define DS_TOT (DINNER * DSTATE)   // 32768
#define NBCX   96                  // packed [x_proj(64) | B(16) | C(16)]

__device__ __forceinline__ float cvt(float v) { return v; }
__device__ __forceinline__ float cvt(bf16 v)  { return __bfloat162float(v); }

template<typename T> __device__ __forceinline__ T sto(float v);
template<> __device__ __forceinline__ float sto<float>(float v) { return v; }
template<> __device__ __forceinline__ bf16  sto<bf16>(float v)  { return __float2bfloat16(v); }

// async global->LDS 16B copy: HW writes lds_base(wave-uniform) + lane*16
__device__ __forceinline__ void gll16(const bf16* g, short* l)
{
    __builtin_amdgcn_global_load_lds(
        (const __attribute__((address_space(1))) unsigned int*)(const void*)g,
        (__attribute__((address_space(3))) unsigned int*)(void*)l,
        16, 0, 0);
}

// -- fused f32->bf16 convert: x | in_proj_w | out_proj_w | dt_proj_w | bcx --
// 8 elems/thread: 2x float4 in, one uint4 (16B) out.
__global__ __launch_bounds__(256)
void cvt_all(const float* __restrict__ a, const float* __restrict__ b,
             const float* __restrict__ c, const float* __restrict__ d,
             const float* __restrict__ xp, const float* __restrict__ Bp,
             const float* __restrict__ Cp,
             bf16* __restrict__ oa, bf16* __restrict__ ob, bf16* __restrict__ oc,
             bf16* __restrict__ od, bf16* __restrict__ obcx,
             int na, int nb, int nc, int nd, int nbcx)
{
    const int idx = (blockIdx.x * 256 + threadIdx.x) * 8;
    const float* src; bf16* dst; int off;
    if (idx < na)                      { src = a; dst = oa; off = idx; }
    else if (idx < na + nb)            { src = b; dst = ob; off = idx - na; }
    else if (idx < na + nb + nc)       { src = c; dst = oc; off = idx - na - nb; }
    else if (idx < na + nb + nc + nd)  { src = d; dst = od; off = idx - na - nb - nc; }
    else if (idx < na+nb+nc+nd+nbcx) {
        off = idx - na - nb - nc - nd;
        const int r = off >> 11, k = off & 2047;
        src = (r < 64) ? (xp + (size_t)r * 2048 + k)
            : (r < 80) ? (Bp + (size_t)(r - 64) * 2048 + k)
                       : (Cp + (size_t)(r - 80) * 2048 + k);
        src -= off;
        dst = obcx;
    } else return;
    const float4 v0 = *(const float4*)(src + off);
    const float4 v1 = *(const float4*)(src + off + 4);
    union { uint4 u; bf16 h[8]; } o;
    o.h[0] = sto<bf16>(v0.x); o.h[1] = sto<bf16>(v0.y);
    o.h[2] = sto<bf16>(v0.z); o.h[3] = sto<bf16>(v0.w);
    o.h[4] = sto<bf16>(v1.x); o.h[5] = sto<bf16>(v1.y);
    o.h[6] = sto<bf16>(v1.z); o.h[7] = sto<bf16>(v1.w);
    *(uint4*)(dst + off) = o.u;
}

// ===================== 256x256 8-phase MFMA GEMM (K1) ======================
// C[m,n] = sum_k A[m,k]*W[n,k], bf16 out split at column `split`.
// BM=BN=256, BK=64, 512 thr = 8 waves (2M x 4N), per-wave 128x64 out.
// LDS 128KB: A_b0 | A_b1 | B_b0 | B_b1, each 256x64 bf16 staged as two
// 128-row halves; tile t lives in buf t&1.
// Swizzle (T2): involution swz(o) = o ^ (((o>>7)&7)<<4) within each 16KB
// half (row = o>>7, 128B rows). global_load_lds dest stays LINEAR; source
// address and ds_read address both apply swz (rule #21).
// Schedule (T3+T4): per iteration (tiles 2i,2i+1) 8 phases; phase =
// {ds_read quadrant, stage 1 half-tile, [vmcnt(4) @ p4/p8], s_barrier,
//  lgkmcnt(0), setprio(1), 16 MFMA, setprio(0), s_barrier}.
#define BAR   __builtin_amdgcn_s_barrier()
#define LGK0  asm volatile("s_waitcnt lgkmcnt(0)" ::: "memory")
#define VM4   asm volatile("s_waitcnt vmcnt(4)" ::: "memory")
#define VM0   asm volatile("s_waitcnt vmcnt(0)" ::: "memory")
#define PRIO1 __builtin_amdgcn_s_setprio(1)
#define PRIO0 __builtin_amdgcn_s_setprio(0)

#define STAGE(PTR, SOFF, REGSH, T, H) \
  { const bf16* s_ = (PTR) + (SOFF) + (size_t)(H)*128*K + (size_t)(T)*64; \
    short* d_ = lds + (REGSH) + (H)*8192 + tid*8; \
    gll16(s_, d_); gll16(s_ + rstep, d_ + 4096); }

#define RD_A(BASE, MH) \
  { _Pragma("unroll") \
    for (int ii = 0; ii < 4; ++ii) { \
      const int fb_ = (BASE) + ((MH)*4 + ii) * 2048; \
      a_[ii][0] = *(const bf16x8*)(ldsB + (fb_ + kc0)); \
      a_[ii][1] = *(const bf16x8*)(ldsB + (fb_ + kc1)); } }

#define RD_B(BASE, NH, B_) \
  { _Pragma("unroll") \
    for (int jj = 0; jj < 2; ++jj) { \
      const int fb_ = (BASE) + ((NH)*2 + jj) * 2048; \
      B_[jj][0] = *(const bf16x8*)(ldsB + (fb_ + kc0)); \
      B_[jj][1] = *(const bf16x8*)(ldsB + (fb_ + kc1)); } }

#define MM(MH, NH, B_) \
  { _Pragma("unroll") \
    for (int ii = 0; ii < 4; ++ii) { \
      _Pragma("unroll") \
      for (int jj = 0; jj < 2; ++jj) { \
        f32x4& c_ = acc[(MH)*4 + ii][(NH)*2 + jj]; \
        c_ = __builtin_amdgcn_mfma_f32_16x16x32_bf16(a_[ii][0], B_[jj][0], c_, 0, 0, 0); \
        c_ = __builtin_amdgcn_mfma_f32_16x16x32_bf16(a_[ii][1], B_[jj][1], c_, 0, 0, 0); } } }

__global__ __launch_bounds__(512, 2)
void gemm256(const bf16* __restrict__ A, const bf16* __restrict__ W,
             bf16* __restrict__ out0, bf16* __restrict__ out1,
             int N, int K, int split)
{
    __shared__ __align__(16) short lds[65536];   // 128 KB

    const int tid  = threadIdx.x;
    const int lane = tid & 63;
    const int wv   = tid >> 6;
    const int wm_i = wv >> 2;      // 0..1
    const int wn_i = wv & 3;       // 0..3
    const int fr   = lane & 15;
    const int C4   = lane >> 4;

    // T1: bijective XCD-aware swizzle of the 1D grid
    int wg = blockIdx.x;
    { const int nwg = gridDim.x;
      const int q = nwg >> 3, r = nwg & 7, x = wg & 7, o = wg >> 3;
      wg = (x < r ? x * (q + 1) : r * (q + 1) + (x - r) * q) + o; }
    const int nbx = N >> 8;
    const int bx = wg % nbx, by = wg / nbx;
    const int m0 = by * 256, n0 = bx * 256;

    // staging per-thread constants (source pre-swizzle = same involution)
    const int lr  = tid >> 3;                                        // 0..63
    const int cbh = ((((tid & 7) << 4) ^ (((tid >> 3) & 7) << 4)) >> 1); // elems
    const size_t aso   = (size_t)(m0 + lr) * K + cbh;
    const size_t bso   = (size_t)(n0 + lr) * K + cbh;
    const size_t rstep = (size_t)64 * K;

    // ds_read per-lane constants (byte offsets, swz applied)
    const char* const ldsB = (const char*)lds;
    const int xk  = (fr & 7) << 4;
    const int kc0 = (C4 * 16) ^ xk;           // kk=0 slice
    const int kc1 = (64 + C4 * 16) ^ xk;      // kk=1 slice
    // region byte bases: A_b0=0, A_b1=32768, B_b0=65536, B_b1=98304
    const int aRB0 = 0     + wm_i * 16384 + fr * 128;
    const int aRB1 = 32768 + wm_i * 16384 + fr * 128;
    const int bRB0 = 65536 + (wn_i >> 1) * 16384 + (wn_i & 1) * 8192 + fr * 128;
    const int bRB1 = 98304 + (wn_i >> 1) * 16384 + (wn_i & 1) * 8192 + fr * 128;

    f32x4  acc[8][4] = {};
    bf16x8 a_[4][2], b0_[2][2], b1_[2][2];

    // prologue: A(0)->A_b0, B(0)->B_b0, B(1)->B_b1; drain; barrier
    STAGE(A, aso, 0,     0, 0); STAGE(A, aso, 0,     0, 1);
    STAGE(W, bso, 32768, 0, 0); STAGE(W, bso, 32768, 0, 1);
    STAGE(W, bso, 49152, 1, 0); STAGE(W, bso, 49152, 1, 1);
    VM0; BAR;

    const int NIT = K >> 7;          // 2 K-tiles (BK=64) per iteration
    for (int it = 0; it < NIT; ++it) {
        const int tA1 = 2 * it + 1;
        const int tN  = 2 * it + 2;
        const bool pf = (it + 1 < NIT);
        // p1: tile 2it quadrant (0,0)
        RD_A(aRB0, 0); RD_B(bRB0, 0, b0_);
        STAGE(A, aso, 16384, tA1, 0);
        BAR; LGK0; PRIO1; MM(0, 0, b0_); PRIO0; BAR;
        // p2: (0,1)
        RD_B(bRB0, 1, b1_);
        STAGE(A, aso, 16384, tA1, 1);
        BAR; LGK0; PRIO1; MM(0, 1, b1_); PRIO0; BAR;
        // p3: (1,0)
        RD_A(aRB0, 1);
        if (pf) STAGE(W, bso, 32768, tN, 0);
        BAR; LGK0; PRIO1; MM(1, 0, b0_); PRIO0; BAR;
        // p4: (1,1)  [counted vmcnt; full drain on last iter]
        if (pf) { STAGE(W, bso, 32768, tN, 1); VM4; } else { VM0; }
        BAR; LGK0; PRIO1; MM(1, 1, b1_); PRIO0; BAR;
        // p5: tile 2it+1 quadrant (0,0)
        RD_A(aRB1, 0); RD_B(bRB1, 0, b0_);
        if (pf) STAGE(A, aso, 0, tN, 0);
        BAR; LGK0; PRIO1; MM(0, 0, b0_); PRIO0; BAR;
        // p6: (0,1)
        RD_B(bRB1, 1, b1_);
        if (pf) STAGE(A, aso, 0, tN, 1);
        BAR; LGK0; PRIO1; MM(0, 1, b1_); PRIO0; BAR;
        // p7: (1,0)
        RD_A(aRB1, 1);
        if (pf) STAGE(W, bso, 49152, 2 * it + 3, 0);
        BAR; LGK0; PRIO1; MM(1, 0, b0_); PRIO0; BAR;
        // p8: (1,1)
        if (pf) { STAGE(W, bso, 49152, 2 * it + 3, 1); VM4; }
        BAR; LGK0; PRIO1; MM(1, 1, b1_); PRIO0; BAR;
    }

    // ---------- epilogue: repack through (dead) LDS, 16B stores ----------
    bf16* cs = (bf16*)lds;                      // 256x256 bf16 = 128KB
    #pragma unroll
    for (int i = 0; i < 8; ++i)
        #pragma unroll
        for (int j = 0; j < 4; ++j)
            #pragma unroll
            for (int r = 0; r < 4; ++r) {
                const int m = wm_i * 128 + i * 16 + C4 * 4 + r;
                const int n = wn_i * 64  + j * 16 + fr;
                cs[m * 256 + (n ^ ((m & 7) << 3))] = sto<bf16>(acc[i][j][r]);
            }
    __syncthreads();
    bf16* dst; int colb;
    if (n0 < split) { dst = out0; colb = n0; }
    else            { dst = out1; colb = n0 - split; }
    #pragma unroll
    for (int g = 0; g < 16; ++g) {
        const int G = tid + 512 * g;
        const int m = G >> 5;
        const int c = G & 31;
        const uint4 v = *(const uint4*)&cs[m * 256 + ((c * 8) ^ ((m & 7) << 3))];
        *(uint4*)&dst[(size_t)(m0 + m) * split + colb + c * 8] = v;
    }
}

// -------- MFMA GEMM: bf16 async-LDS dbuf staging + vectorized epilogue -----
// (kept for K3/K4/K6 — grids too small for 256^2 tiles)
template<typename TO, int SPLITK, int EPI>
__global__ __launch_bounds__(256)
void gemm_mfma(const bf16* __restrict__ A, const bf16* __restrict__ W,
               TO* __restrict__ out, TO* __restrict__ out2,
               const float* __restrict__ bias,
               int M, int N, int K, int split, int kchunk)
{
    __shared__ __align__(16) short smem[16384];   // 32 KB
    short* As = smem;            // [2][4096]
    short* Bs = smem + 8192;     // [2][4096]

    const int tid  = threadIdx.x;
    const int lane = tid & 63;
    const int wv   = tid >> 6;
    const int wm = (wv & 1) * 64;
    const int wn = (wv >> 1) * 64;
    const int m0 = blockIdx.y * 128;
    const int n0 = blockIdx.x * 128;

    const int p0 = wv * 64 + lane;
    const int p1 = p0 + 256;
    const int r0 = p0 >> 2, c0 = (p0 & 3) ^ ((r0 >> 1) & 3);
    const int r1 = p1 >> 2, c1 = (p1 & 3) ^ ((r1 >> 1) & 3);

    const bf16* srcA0 = A + (size_t)(m0 + r0) * K + c0 * 8;
    const bf16* srcA1 = A + (size_t)(m0 + r1) * K + c1 * 8;
    int nr0 = n0 + r0; if (nr0 >= N) nr0 = N - 1;
    int nr1 = n0 + r1; if (nr1 >= N) nr1 = N - 1;
    const bf16* srcB0 = W + (size_t)nr0 * K + c0 * 8;
    const bf16* srcB1 = W + (size_t)nr1 * K + c1 * 8;

    const int C4 = lane >> 4;
    const int fr = lane & 15;
    int aOff[4], bOff[4];
    #pragma unroll
    for (int i = 0; i < 4; ++i) {
        const int R = wm + i * 16 + fr;
        aOff[i] = R * 32 + ((C4 ^ ((R >> 1) & 3)) << 3);
    }
    #pragma unroll
    for (int j = 0; j < 4; ++j) {
        const int R = wn + j * 16 + fr;
        bOff[j] = R * 32 + ((C4 ^ ((R >> 1) & 3)) << 3);
    }

    f32x4 acc[4][4] = {};

    const int kb  = blockIdx.z * kchunk;
    const int nit = kchunk / 32;

    // prologue: stage tile 0 into buffer 0
    gll16(srcA0 + kb, &As[wv * 512]);
    gll16(srcA1 + kb, &As[(wv + 4) * 512]);
    gll16(srcB0 + kb, &Bs[wv * 512]);
    gll16(srcB1 + kb, &Bs[(wv + 4) * 512]);

    for (int it = 0; it < nit; ++it) {
        __syncthreads();                 // buf p ready; prior reads of buf q done
        const int p = it & 1;
        if (it + 1 < nit) {
            const int q  = p ^ 1;
            const int k1 = kb + (it + 1) * 32;
            gll16(srcA0 + k1, &As[q * 4096 + wv * 512]);
            gll16(srcA1 + k1, &As[q * 4096 + (wv + 4) * 512]);
            gll16(srcB0 + k1, &Bs[q * 4096 + wv * 512]);
            gll16(srcB1 + k1, &Bs[q * 4096 + (wv + 4) * 512]);
        }
        bf16x8 af[4], bfr[4];
        #pragma unroll
        for (int i = 0; i < 4; ++i) af[i]  = *(const bf16x8*)&As[p * 4096 + aOff[i]];
        #pragma unroll
        for (int j = 0; j < 4; ++j) bfr[j] = *(const bf16x8*)&Bs[p * 4096 + bOff[j]];
        #pragma unroll
        for (int i = 0; i < 4; ++i)
            #pragma unroll
            for (int j = 0; j < 4; ++j)
                acc[i][j] = __builtin_amdgcn_mfma_f32_16x16x32_bf16(af[i], bfr[j], acc[i][j], 0, 0, 0);
    }

    __syncthreads();   // all LDS reads done; smem free for epilogue repack

    const int rb = (lane >> 4) * 4;

    if constexpr (sizeof(TO) == 2) {
        // bf16 out: one pass, 128x128 bf16 = 32 KB
        bf16* cs = (bf16*)smem;
        #pragma unroll
        for (int i = 0; i < 4; ++i)
            #pragma unroll
            for (int j = 0; j < 4; ++j)
                #pragma unroll
                for (int r = 0; r < 4; ++r) {
                    const int m = wm + i * 16 + rb + r;
                    const int n = wn + j * 16 + fr;
                    float v = acc[i][j][r];
                    if (EPI == 1) {
                        v += bias[n0 + n];
                        // fast softplus via v_exp/v_log (bf16-out quantization
                        // dwarfs ~1ulp intrinsic error; libm was 42us, R1)
                        v = (v > 20.f) ? v : __logf(1.f + __expf(v));
                    }
                    const int key = (m >> 2) & 3;
                    cs[m * 128 + (n ^ ((key & 1) << 4) ^ ((key >> 1) << 5))] = sto<bf16>(v);
                }
        __syncthreads();
        TO* ob; int nc0; int ostr;
        if (split > 0) {
            if (n0 < split) { ob = out;  nc0 = n0;         }
            else            { ob = out2; nc0 = n0 - split; }
            ostr = split;
        } else { ob = out; nc0 = n0; ostr = N; }
        #pragma unroll
        for (int g8 = 0; g8 < 8; ++g8) {
            const int G = tid + 256 * g8;
            const int mrow = G >> 4;
            const int cg = G & 15;
            const int key = (mrow >> 2) & 3;
            const int nst = (cg * 8) ^ ((key & 1) << 4) ^ ((key >> 1) << 5);
            if (n0 + nst < N) {
                const uint4 val = *(const uint4*)&cs[mrow * 128 + cg * 8];
                *(uint4*)&ob[(size_t)(m0 + mrow) * ostr + nc0 + nst] = val;
            }
        }
    } else {
        // f32 out: two n-half passes of 128x64 f32 = 32 KB
        float* fs = (float*)smem;
        float* obase = SPLITK ? ((float*)out + (size_t)blockIdx.z * M * N) : (float*)out;
        #pragma unroll
        for (int ph = 0; ph < 2; ++ph) {
            __syncthreads();
            if ((wn >> 6) == ph) {       // the 2 waves owning this n-half write
                #pragma unroll
                for (int i = 0; i < 4; ++i)
                    #pragma unroll
                    for (int j = 0; j < 4; ++j)
                        #pragma unroll
                        for (int r = 0; r < 4; ++r) {
                            const int m = wm + i * 16 + rb + r;
                            const int qq = j * 16 + fr;
                            fs[m * 64 + (qq ^ (((m >> 2) & 1) << 4))] = acc[i][j][r];
                        }
            }
            __syncthreads();
            #pragma unroll
            for (int g8 = 0; g8 < 8; ++g8) {
                const int G = tid + 256 * g8;
                const int mrow = G >> 4;
                const int cg = G & 15;
                const int qst = (cg * 4) ^ (((mrow >> 2) & 1) << 4);
                const int n_g = 64 * ph + qst;
                if (n0 + n_g < N) {
                    const float4 val = *(const float4*)&fs[mrow * 64 + cg * 4];
                    *(float4*)&obase[(size_t)(m0 + mrow) * N + n0 + n_g] = val;
                }
            }
        }
    }
}

// sum 8 split-K partials of the bcx projection; emit xr (bf16, 4096x64)
// and B|C (f32, 4096x32).
__global__ __launch_bounds__(256)
void reduce_bcx(const float* __restrict__ P8, bf16* __restrict__ xr,
                float* __restrict__ BC)
{
    const int u = blockIdx.x * 256 + threadIdx.x;   // over MROWS*NBCX
    const int m = u / NBCX;
    const int n = u - m * NBCX;
    float s = 0.f;
    #pragma unroll
    for (int k = 0; k < 8; ++k) s += P8[(size_t)k * MROWS * NBCX + u];
    if (n < 64) xr[(size_t)m * 64 + n] = sto<bf16>(s);
    else        BC[(size_t)m * 32 + (n - 64)] = s;
}

// causal depthwise conv (d_conv=4) + bias + SiLU, 8 elems/thread, 16B ldst
__global__ __launch_bounds__(256)
void conv_silu(const bf16* __restrict__ x_in, const float* __restrict__ cw,
               const float* __restrict__ cb, bf16* __restrict__ x_conv)
{
    const size_t i8 = (size_t)(blockIdx.x * 256 + threadIdx.x) * 8;
    const int d = (int)(i8 & (DINNER - 1));
    const int t = (int)((i8 >> 11) & (LSEQ - 1));
    uint4 v[4];
    const uint4 z4 = make_uint4(0, 0, 0, 0);
    v[3] = *(const uint4*)(x_in + i8);
    v[2] = (t >= 1) ? *(const uint4*)(x_in + i8 - 1 * DINNER) : z4;
    v[1] = (t >= 2) ? *(const uint4*)(x_in + i8 - 2 * DINNER) : z4;
    v[0] = (t >= 3) ? *(const uint4*)(x_in + i8 - 3 * DINNER) : z4;
    const bf16* e0 = (const bf16*)&v[0];
    const bf16* e1 = (const bf16*)&v[1];
    const bf16* e2 = (const bf16*)&v[2];
    const bf16* e3 = (const bf16*)&v[3];
    bf16 ob[8];
    #pragma unroll
    for (int e = 0; e < 8; ++e) {
        const float4 w = *(const float4*)(cw + (size_t)(d + e) * 4);
        float a = cb[d + e];
        a = fmaf(w.x, cvt(e0[e]), a);
        a = fmaf(w.y, cvt(e1[e]), a);
        a = fmaf(w.z, cvt(e2[e]), a);
        a = fmaf(w.w, cvt(e3[e]), a);
        const float sig = 1.f / (1.f + __expf(-a));
        ob[e] = sto<bf16>(a * sig);
    }
    *(uint4*)(x_conv + i8) = *(const uint4*)ob;
}

// ---------------- chunked two-phase selective scan ----------------
// B/C rows in BC buffer: row stride 32 f32, B at +0, C at +16.
// R5: 2 d's per thread (d, d+64): doubles per-wave MLP/ILP on the scalar
// bf16 loads, B/C broadcast rows register-shared across both d's.
// grid (NCHUNK, DINNER/128, BSZ), 64-thr blocks.
__global__ __launch_bounds__(64)
void scan_phase_a(const bf16* __restrict__ x_conv, const bf16* __restrict__ dt,
                  const float* __restrict__ BC, const float* __restrict__ A_log,
                  float* __restrict__ hend, float* __restrict__ Pprod)
{
    const int lane = threadIdx.x;
    const int c = blockIdx.x;
    const int d0 = blockIdx.y * 128 + lane;     // second d = d0 + 64
    const int b = blockIdx.z;

    float Af[2][DSTATE];
    #pragma unroll
    for (int u = 0; u < 2; ++u)
        #pragma unroll
        for (int s = 0; s < DSTATE; ++s)
            Af[u][s] = -__expf(A_log[(d0 + u * 64) * DSTATE + s]);

    float h[2][DSTATE], P[2][DSTATE];
    #pragma unroll
    for (int u = 0; u < 2; ++u)
        #pragma unroll
        for (int s = 0; s < DSTATE; ++s) { h[u][s] = 0.f; P[u][s] = 1.f; }

    const size_t base = ((size_t)b * LSEQ + (size_t)c * CHUNK) * DINNER + d0;
    const bf16* xp  = x_conv + base;
    const bf16* dtp = dt + base;
    const float* Bp = BC + ((size_t)b * LSEQ + (size_t)c * CHUNK) * 32;

    for (int t0 = 0; t0 < CHUNK; t0 += 4) {
        float xg[2][4], dtg[2][4];
        #pragma unroll
        for (int j = 0; j < 4; ++j) {
            xg[0][j]  = cvt(xp [(size_t)(t0 + j) * DINNER]);
            xg[1][j]  = cvt(xp [(size_t)(t0 + j) * DINNER + 64]);
            dtg[0][j] = cvt(dtp[(size_t)(t0 + j) * DINNER]);
            dtg[1][j] = cvt(dtp[(size_t)(t0 + j) * DINNER + 64]);
        }
        #pragma unroll
        for (int j = 0; j < 4; ++j) {
            float Bv[DSTATE];
            const float* Br = Bp + (size_t)(t0 + j) * 32;
            *(float4*)(&Bv[0])  = *(const float4*)(Br + 0);
            *(float4*)(&Bv[4])  = *(const float4*)(Br + 4);
            *(float4*)(&Bv[8])  = *(const float4*)(Br + 8);
            *(float4*)(&Bv[12]) = *(const float4*)(Br + 12);
            #pragma unroll
            for (int u = 0; u < 2; ++u) {
                const float dtv = dtg[u][j];
                const float dtx = dtv * xg[u][j];
                #pragma unroll
                for (int s = 0; s < DSTATE; ++s) {
                    const float a = fmaf(dtv, Af[u][s], 1.0f);
                    h[u][s] = fmaf(h[u][s], a, dtx * Bv[s]);
                    P[u][s] *= a;
                }
            }
        }
    }

    #pragma unroll
    for (int u = 0; u < 2; ++u) {
        const size_t oidx = (((size_t)b * NCHUNK + c) * DINNER + d0 + u * 64) * DSTATE;
        #pragma unroll
        for (int s = 0; s < DSTATE; ++s) {
            hend [oidx + s] = h[u][s];
            Pprod[oidx + s] = P[u][s];
        }
    }
}

__global__ __launch_bounds__(256)
void scan_combine(float* __restrict__ hend, const float* __restrict__ Pprod)
{
    const int u = blockIdx.x * 256 + threadIdx.x;
    const int b = blockIdx.y;
    float h = 0.f;
    for (int c = 0; c < NCHUNK; ++c) {
        const size_t idx = ((size_t)b * NCHUNK + c) * DS_TOT + u;
        const float he = hend[idx];
        const float p  = Pprod[idx];
        hend[idx] = h;
        h = fmaf(p, h, he);
    }
}

__global__ __launch_bounds__(64)
void scan_phase_c(const bf16* __restrict__ x_conv, const bf16* __restrict__ dt,
                  const float* __restrict__ BC,
                  const float* __restrict__ A_log, const float* __restrict__ Dw,
                  const float* __restrict__ hin, bf16* __restrict__ zy)
{
    const int lane = threadIdx.x;
    const int c = blockIdx.x;
    const int d0 = blockIdx.y * 128 + lane;     // second d = d0 + 64
    const int b = blockIdx.z;

    float Af[2][DSTATE];
    #pragma unroll
    for (int u = 0; u < 2; ++u)
        #pragma unroll
        for (int s = 0; s < DSTATE; ++s)
            Af[u][s] = -__expf(A_log[(d0 + u * 64) * DSTATE + s]);
    const float Dv0 = Dw[d0];
    const float Dv1 = Dw[d0 + 64];

    float h[2][DSTATE];
    #pragma unroll
    for (int u = 0; u < 2; ++u) {
        const size_t hidx = (((size_t)b * NCHUNK + c) * DINNER + d0 + u * 64) * DSTATE;
        #pragma unroll
        for (int s = 0; s < DSTATE; ++s) h[u][s] = hin[hidx + s];
    }

    const size_t base = ((size_t)b * LSEQ + (size_t)c * CHUNK) * DINNER + d0;
    const bf16* xp  = x_conv + base;
    const bf16* dtp = dt + base;
    bf16*       zp  = zy + base;
    const float* Bp = BC + ((size_t)b * LSEQ + (size_t)c * CHUNK) * 32;
    const float* Cp = Bp + 16;

    for (int t0 = 0; t0 < CHUNK; t0 += 4) {
        float xg[2][4], dtg[2][4], zg[2][4];
        #pragma unroll
        for (int j = 0; j < 4; ++j) {
            xg[0][j]  = cvt(xp [(size_t)(t0 + j) * DINNER]);
            xg[1][j]  = cvt(xp [(size_t)(t0 + j) * DINNER + 64]);
            dtg[0][j] = cvt(dtp[(size_t)(t0 + j) * DINNER]);
            dtg[1][j] = cvt(dtp[(size_t)(t0 + j) * DINNER + 64]);
            zg[0][j]  = cvt(zp [(size_t)(t0 + j) * DINNER]);
            zg[1][j]  = cvt(zp [(size_t)(t0 + j) * DINNER + 64]);
        }
        #pragma unroll
        for (int j = 0; j < 4; ++j) {
            float Bv[DSTATE], Cv[DSTATE];
            const float* Br = Bp + (size_t)(t0 + j) * 32;
            const float* Cr = Cp + (size_t)(t0 + j) * 32;
            *(float4*)(&Bv[0])  = *(const float4*)(Br + 0);
            *(float4*)(&Bv[4])  = *(const float4*)(Br + 4);
            *(float4*)(&Bv[8])  = *(const float4*)(Br + 8);
            *(float4*)(&Bv[12]) = *(const float4*)(Br + 12);
            *(float4*)(&Cv[0])  = *(const float4*)(Cr + 0);
            *(float4*)(&Cv[4])  = *(const float4*)(Cr + 4);
            *(float4*)(&Cv[8])  = *(const float4*)(Cr + 8);
            *(float4*)(&Cv[12]) = *(const float4*)(Cr + 12);
            #pragma unroll
            for (int u = 0; u < 2; ++u) {
                const float dtv = dtg[u][j];
                const float dtx = dtv * xg[u][j];
                float y = 0.f;
                #pragma unroll
                for (int s = 0; s < DSTATE; ++s) {
                    const float a = fmaf(dtv, Af[u][s], 1.0f);
                    h[u][s] = fmaf(h[u][s], a, dtx * Bv[s]);
                    y = fmaf(h[u][s], Cv[s], y);
                }
                const float zv = zg[u][j];
                const float sig = 1.f / (1.f + __expf(-zv));
                const float Dv = (u == 0) ? Dv0 : Dv1;
                zp[(size_t)(t0 + j) * DINNER + u * 64] =
                    sto<bf16>(fmaf(Dv, xg[u][j], y) * (zv * sig));
            }
        }
    }
}

extern "C" void kernel_launch(void* const* d_in, const int* in_sizes, int n_in,
                              void* d_out, int out_size, void* d_ws, size_t ws_size,
                              hipStream_t stream)
{
    const float* x          = (const float*)d_in[0];
    const float* in_proj_w  = (const float*)d_in[1];
    const float* conv_w     = (const float*)d_in[2];
    const float* conv_b     = (const float*)d_in[3];
    const float* A_log      = (const float*)d_in[4];
    const float* Dw         = (const float*)d_in[5];
    const float* dt_proj_w  = (const float*)d_in[6];
    const float* dt_proj_b  = (const float*)d_in[7];
    const float* x_proj_w   = (const float*)d_in[8];
    const float* B_proj_w   = (const float*)d_in[9];
    const float* C_proj_w   = (const float*)d_in[10];
    const float* out_proj_w = (const float*)d_in[11];
    float* out = (float*)d_out;

    // workspace (~93 MB, with aliasing) — identical to R9 layout
    const size_t MD = (size_t)MROWS * DINNER;
    bf16* buf0 = (bf16*)d_ws;                        // x_in -> P8 -> dt
    bf16* buf1 = buf0 + MD;                          // z -> y (in place)
    bf16* buf2 = buf1 + MD;                          // x_conv
    bf16* xbf  = buf2 + MD;                          // x bf16 (dead after K1)
    bf16* wbf1 = xbf  + (size_t)MROWS * DMODEL;      // in_proj bf16
    bf16* wbf2 = wbf1 + (size_t)2 * DINNER * DMODEL; // out_proj bf16
    bf16* wbc  = wbf2 + (size_t)DMODEL * DINNER;     // packed bcx weights bf16
    bf16* wdt  = wbc  + (size_t)NBCX * DINNER;       // dt_proj_w bf16
    float* hend = (float*)(wdt + (size_t)DINNER * DTRANK);
    float* Pp   = hend + (size_t)BSZ * NCHUNK * DS_TOT;
    // aliases over dead regions:
    bf16*  xr_bf = xbf;                              // 4096x64 bf16 (xbf dead after K1)
    float* BCbuf = (float*)(xbf + (size_t)MROWS * DTRANK); // 4096x32 f32
    float* P8 = (float*)buf0;  // 12.58 MB over buf0 (16.78): x_in dead after conv

    dim3 blk(256);
    const int na = MROWS * DMODEL;
    const int nb = 2 * DINNER * DMODEL;
    const int nc = DMODEL * DINNER;
    const int nd = DINNER * DTRANK;
    const int nbcx = NBCX * DINNER;

    // fused f32->bf16 converts + weight pack (8 elems/thread)
    cvt_all<<<(na + nb + nc + nd + nbcx) / 2048, blk, 0, stream>>>(
        x, in_proj_w, out_proj_w, dt_proj_w, x_proj_w, B_proj_w, C_proj_w,
        xbf, wbf1, wbf2, wdt, wbc, na, nb, nc, nd, nbcx);

    // K1: xz = x @ in_proj_w^T — 256^2 8-phase MFMA, split into x_in | z
    gemm256<<<dim3((MROWS / 256) * (2 * DINNER / 256)), dim3(512), 0, stream>>>(
        xbf, wbf1, buf0, buf1, 2 * DINNER, DMODEL, DINNER);

    // K2: causal depthwise conv + SiLU
    conv_silu<<<(MROWS * DINNER) / (256 * 8), blk, 0, stream>>>(buf0, conv_w, conv_b, buf2);

    // K3: fused xr|B|C projection, split-K=8, partials -> P8 (over dead x_in)
    gemm_mfma<float, 1, 0><<<dim3(1, MROWS / 128, 8), blk, 0, stream>>>(
        buf2, wbc, P8, (float*)nullptr, nullptr, MROWS, NBCX, DINNER, 0, DINNER / 8);

    // reduce partials -> xr (bf16) + B|C (f32)
    reduce_bcx<<<(MROWS * NBCX) / 256, blk, 0, stream>>>(P8, xr_bf, BCbuf);

    // K4: dt = softplus(xr @ dt_proj_w^T + b)  (MFMA, K=64) -> buf0 (over dead P8)
    gemm_mfma<bf16, 0, 1><<<dim3(DINNER / 128, MROWS / 128, 1), blk, 0, stream>>>(
        xr_bf, wdt, buf0, (bf16*)nullptr, dt_proj_b, MROWS, DINNER, DTRANK, 0, DTRANK);

    // K5: chunked two-phase selective scan (y over z in place in buf1)
    scan_phase_a<<<dim3(NCHUNK, DINNER / 128, BSZ), dim3(64), 0, stream>>>(
        buf2, buf0, BCbuf, A_log, hend, Pp);
    scan_combine<<<dim3(DS_TOT / 256, BSZ), dim3(256), 0, stream>>>(hend, Pp);
    scan_phase_c<<<dim3(NCHUNK, DINNER / 128, BSZ), dim3(64), 0, stream>>>(
        buf2, buf0, BCbuf, A_log, Dw, hend, buf1);

    // K6: out = y @ out_proj_w^T (MFMA dbuf) -> f32 d_out
    gemm_mfma<float, 0, 0><<<dim3(DMODEL / 128, MROWS / 128, 1), blk, 0, stream>>>(
        buf1, wbf2, out, (float*)nullptr, nullptr, MROWS, DMODEL, DINNER, 0, DINNER);
}

// Round 6
// 287.110 us; speedup vs baseline: 1.1516x; 1.1516x over previous
//
#include <hip/hip_runtime.h>
#include <hip/hip_bf16.h>
#include <math.h>

using bf16 = __hip_bfloat16;
typedef short bf16x8 __attribute__((ext_vector_type(8)));
typedef float f32x4  __attribute__((ext_vector_type(4)));

#define DMODEL 1024
#define DSTATE 16
#define DCONV  4
#define DINNER 2048
#define DTRANK 64
#define BSZ    2
#define LSEQ   2048
#define MROWS  (BSZ*LSEQ)   // 4096

#define NCHUNK 32
#define CHUNK  (LSEQ / NCHUNK)     // 64
#define DS_TOT (DINNER * DSTATE)   // 32768
#define NBCX   96                  // packed [x_proj(64) | B(16) | C(16)]

__device__ __forceinline__ float cvt(float v) { return v; }
__device__ __forceinline__ float cvt(bf16 v)  { return __bfloat162float(v); }

template<typename T> __device__ __forceinline__ T sto(float v);
template<> __device__ __forceinline__ float sto<float>(float v) { return v; }
template<> __device__ __forceinline__ bf16  sto<bf16>(float v)  { return __float2bfloat16(v); }

// async global->LDS 16B copy: HW writes lds_base(wave-uniform) + lane*16
__device__ __forceinline__ void gll16(const bf16* g, short* l)
{
    __builtin_amdgcn_global_load_lds(
        (const __attribute__((address_space(1))) unsigned int*)(const void*)g,
        (__attribute__((address_space(3))) unsigned int*)(void*)l,
        16, 0, 0);
}

// -- fused f32->bf16 convert: x | in_proj_w | out_proj_w | dt_proj_w | bcx --
// 8 elems/thread: 2x float4 in, one uint4 (16B) out.
__global__ __launch_bounds__(256)
void cvt_all(const float* __restrict__ a, const float* __restrict__ b,
             const float* __restrict__ c, const float* __restrict__ d,
             const float* __restrict__ xp, const float* __restrict__ Bp,
             const float* __restrict__ Cp,
             bf16* __restrict__ oa, bf16* __restrict__ ob, bf16* __restrict__ oc,
             bf16* __restrict__ od, bf16* __restrict__ obcx,
             int na, int nb, int nc, int nd, int nbcx)
{
    const int idx = (blockIdx.x * 256 + threadIdx.x) * 8;
    const float* src; bf16* dst; int off;
    if (idx < na)                      { src = a; dst = oa; off = idx; }
    else if (idx < na + nb)            { src = b; dst = ob; off = idx - na; }
    else if (idx < na + nb + nc)       { src = c; dst = oc; off = idx - na - nb; }
    else if (idx < na + nb + nc + nd)  { src = d; dst = od; off = idx - na - nb - nc; }
    else if (idx < na+nb+nc+nd+nbcx) {
        off = idx - na - nb - nc - nd;
        const int r = off >> 11, k = off & 2047;
        src = (r < 64) ? (xp + (size_t)r * 2048 + k)
            : (r < 80) ? (Bp + (size_t)(r - 64) * 2048 + k)
                       : (Cp + (size_t)(r - 80) * 2048 + k);
        src -= off;
        dst = obcx;
    } else return;
    const float4 v0 = *(const float4*)(src + off);
    const float4 v1 = *(const float4*)(src + off + 4);
    union { uint4 u; bf16 h[8]; } o;
    o.h[0] = sto<bf16>(v0.x); o.h[1] = sto<bf16>(v0.y);
    o.h[2] = sto<bf16>(v0.z); o.h[3] = sto<bf16>(v0.w);
    o.h[4] = sto<bf16>(v1.x); o.h[5] = sto<bf16>(v1.y);
    o.h[6] = sto<bf16>(v1.z); o.h[7] = sto<bf16>(v1.w);
    *(uint4*)(dst + off) = o.u;
}

// ===================== 256x256 8-phase MFMA GEMM (K1) ======================
// C[m,n] = sum_k A[m,k]*W[n,k], bf16 out split at column `split`.
// BM=BN=256, BK=64, 512 thr = 8 waves (2M x 4N), per-wave 128x64 out.
// LDS 128KB: A_b0 | A_b1 | B_b0 | B_b1, each 256x64 bf16 staged as two
// 128-row halves; tile t lives in buf t&1.
// Swizzle (T2): involution swz(o) = o ^ (((o>>7)&7)<<4) within each 16KB
// half (row = o>>7, 128B rows). global_load_lds dest stays LINEAR; source
// address and ds_read address both apply swz (rule #21).
// Schedule (T3+T4): per iteration (tiles 2i,2i+1) 8 phases; phase =
// {ds_read quadrant, stage 1 half-tile, [vmcnt(4) @ p4/p8], s_barrier,
//  lgkmcnt(0), setprio(1), 16 MFMA, setprio(0), s_barrier}.
#define BAR   __builtin_amdgcn_s_barrier()
#define LGK0  asm volatile("s_waitcnt lgkmcnt(0)" ::: "memory")
#define VM4   asm volatile("s_waitcnt vmcnt(4)" ::: "memory")
#define VM0   asm volatile("s_waitcnt vmcnt(0)" ::: "memory")
#define PRIO1 __builtin_amdgcn_s_setprio(1)
#define PRIO0 __builtin_amdgcn_s_setprio(0)

#define STAGE(PTR, SOFF, REGSH, T, H) \
  { const bf16* s_ = (PTR) + (SOFF) + (size_t)(H)*128*K + (size_t)(T)*64; \
    short* d_ = lds + (REGSH) + (H)*8192 + tid*8; \
    gll16(s_, d_); gll16(s_ + rstep, d_ + 4096); }

#define RD_A(BASE, MH) \
  { _Pragma("unroll") \
    for (int ii = 0; ii < 4; ++ii) { \
      const int fb_ = (BASE) + ((MH)*4 + ii) * 2048; \
      a_[ii][0] = *(const bf16x8*)(ldsB + (fb_ + kc0)); \
      a_[ii][1] = *(const bf16x8*)(ldsB + (fb_ + kc1)); } }

#define RD_B(BASE, NH, B_) \
  { _Pragma("unroll") \
    for (int jj = 0; jj < 2; ++jj) { \
      const int fb_ = (BASE) + ((NH)*2 + jj) * 2048; \
      B_[jj][0] = *(const bf16x8*)(ldsB + (fb_ + kc0)); \
      B_[jj][1] = *(const bf16x8*)(ldsB + (fb_ + kc1)); } }

#define MM(MH, NH, B_) \
  { _Pragma("unroll") \
    for (int ii = 0; ii < 4; ++ii) { \
      _Pragma("unroll") \
      for (int jj = 0; jj < 2; ++jj) { \
        f32x4& c_ = acc[(MH)*4 + ii][(NH)*2 + jj]; \
        c_ = __builtin_amdgcn_mfma_f32_16x16x32_bf16(a_[ii][0], B_[jj][0], c_, 0, 0, 0); \
        c_ = __builtin_amdgcn_mfma_f32_16x16x32_bf16(a_[ii][1], B_[jj][1], c_, 0, 0, 0); } } }

__global__ __launch_bounds__(512, 2)
void gemm256(const bf16* __restrict__ A, const bf16* __restrict__ W,
             bf16* __restrict__ out0, bf16* __restrict__ out1,
             int N, int K, int split)
{
    __shared__ __align__(16) short lds[65536];   // 128 KB

    const int tid  = threadIdx.x;
    const int lane = tid & 63;
    const int wv   = tid >> 6;
    const int wm_i = wv >> 2;      // 0..1
    const int wn_i = wv & 3;       // 0..3
    const int fr   = lane & 15;
    const int C4   = lane >> 4;

    // T1: bijective XCD-aware swizzle of the 1D grid
    int wg = blockIdx.x;
    { const int nwg = gridDim.x;
      const int q = nwg >> 3, r = nwg & 7, x = wg & 7, o = wg >> 3;
      wg = (x < r ? x * (q + 1) : r * (q + 1) + (x - r) * q) + o; }
    const int nbx = N >> 8;
    const int bx = wg % nbx, by = wg / nbx;
    const int m0 = by * 256, n0 = bx * 256;

    // staging per-thread constants (source pre-swizzle = same involution)
    const int lr  = tid >> 3;                                        // 0..63
    const int cbh = ((((tid & 7) << 4) ^ (((tid >> 3) & 7) << 4)) >> 1); // elems
    const size_t aso   = (size_t)(m0 + lr) * K + cbh;
    const size_t bso   = (size_t)(n0 + lr) * K + cbh;
    const size_t rstep = (size_t)64 * K;

    // ds_read per-lane constants (byte offsets, swz applied)
    const char* const ldsB = (const char*)lds;
    const int xk  = (fr & 7) << 4;
    const int kc0 = (C4 * 16) ^ xk;           // kk=0 slice
    const int kc1 = (64 + C4 * 16) ^ xk;      // kk=1 slice
    // region byte bases: A_b0=0, A_b1=32768, B_b0=65536, B_b1=98304
    const int aRB0 = 0     + wm_i * 16384 + fr * 128;
    const int aRB1 = 32768 + wm_i * 16384 + fr * 128;
    const int bRB0 = 65536 + (wn_i >> 1) * 16384 + (wn_i & 1) * 8192 + fr * 128;
    const int bRB1 = 98304 + (wn_i >> 1) * 16384 + (wn_i & 1) * 8192 + fr * 128;

    f32x4  acc[8][4] = {};
    bf16x8 a_[4][2], b0_[2][2], b1_[2][2];

    // prologue: A(0)->A_b0, B(0)->B_b0, B(1)->B_b1; drain; barrier
    STAGE(A, aso, 0,     0, 0); STAGE(A, aso, 0,     0, 1);
    STAGE(W, bso, 32768, 0, 0); STAGE(W, bso, 32768, 0, 1);
    STAGE(W, bso, 49152, 1, 0); STAGE(W, bso, 49152, 1, 1);
    VM0; BAR;

    const int NIT = K >> 7;          // 2 K-tiles (BK=64) per iteration
    for (int it = 0; it < NIT; ++it) {
        const int tA1 = 2 * it + 1;
        const int tN  = 2 * it + 2;
        const bool pf = (it + 1 < NIT);
        // p1: tile 2it quadrant (0,0)
        RD_A(aRB0, 0); RD_B(bRB0, 0, b0_);
        STAGE(A, aso, 16384, tA1, 0);
        BAR; LGK0; PRIO1; MM(0, 0, b0_); PRIO0; BAR;
        // p2: (0,1)
        RD_B(bRB0, 1, b1_);
        STAGE(A, aso, 16384, tA1, 1);
        BAR; LGK0; PRIO1; MM(0, 1, b1_); PRIO0; BAR;
        // p3: (1,0)
        RD_A(aRB0, 1);
        if (pf) STAGE(W, bso, 32768, tN, 0);
        BAR; LGK0; PRIO1; MM(1, 0, b0_); PRIO0; BAR;
        // p4: (1,1)  [counted vmcnt; full drain on last iter]
        if (pf) { STAGE(W, bso, 32768, tN, 1); VM4; } else { VM0; }
        BAR; LGK0; PRIO1; MM(1, 1, b1_); PRIO0; BAR;
        // p5: tile 2it+1 quadrant (0,0)
        RD_A(aRB1, 0); RD_B(bRB1, 0, b0_);
        if (pf) STAGE(A, aso, 0, tN, 0);
        BAR; LGK0; PRIO1; MM(0, 0, b0_); PRIO0; BAR;
        // p6: (0,1)
        RD_B(bRB1, 1, b1_);
        if (pf) STAGE(A, aso, 0, tN, 1);
        BAR; LGK0; PRIO1; MM(0, 1, b1_); PRIO0; BAR;
        // p7: (1,0)
        RD_A(aRB1, 1);
        if (pf) STAGE(W, bso, 49152, 2 * it + 3, 0);
        BAR; LGK0; PRIO1; MM(1, 0, b0_); PRIO0; BAR;
        // p8: (1,1)
        if (pf) { STAGE(W, bso, 49152, 2 * it + 3, 1); VM4; }
        BAR; LGK0; PRIO1; MM(1, 1, b1_); PRIO0; BAR;
    }

    // ---------- epilogue: repack through (dead) LDS, 16B stores ----------
    bf16* cs = (bf16*)lds;                      // 256x256 bf16 = 128KB
    #pragma unroll
    for (int i = 0; i < 8; ++i)
        #pragma unroll
        for (int j = 0; j < 4; ++j)
            #pragma unroll
            for (int r = 0; r < 4; ++r) {
                const int m = wm_i * 128 + i * 16 + C4 * 4 + r;
                const int n = wn_i * 64  + j * 16 + fr;
                cs[m * 256 + (n ^ ((m & 7) << 3))] = sto<bf16>(acc[i][j][r]);
            }
    __syncthreads();
    bf16* dst; int colb;
    if (n0 < split) { dst = out0; colb = n0; }
    else            { dst = out1; colb = n0 - split; }
    #pragma unroll
    for (int g = 0; g < 16; ++g) {
        const int G = tid + 512 * g;
        const int m = G >> 5;
        const int c = G & 31;
        const uint4 v = *(const uint4*)&cs[m * 256 + ((c * 8) ^ ((m & 7) << 3))];
        *(uint4*)&dst[(size_t)(m0 + m) * split + colb + c * 8] = v;
    }
}

// -------- MFMA GEMM: bf16 async-LDS dbuf staging + vectorized epilogue -----
// (kept for K3/K4/K6 — grids too small for 256^2 tiles)
template<typename TO, int SPLITK, int EPI>
__global__ __launch_bounds__(256)
void gemm_mfma(const bf16* __restrict__ A, const bf16* __restrict__ W,
               TO* __restrict__ out, TO* __restrict__ out2,
               const float* __restrict__ bias,
               int M, int N, int K, int split, int kchunk)
{
    __shared__ __align__(16) short smem[16384];   // 32 KB
    short* As = smem;            // [2][4096]
    short* Bs = smem + 8192;     // [2][4096]

    const int tid  = threadIdx.x;
    const int lane = tid & 63;
    const int wv   = tid >> 6;
    const int wm = (wv & 1) * 64;
    const int wn = (wv >> 1) * 64;
    const int m0 = blockIdx.y * 128;
    const int n0 = blockIdx.x * 128;

    const int p0 = wv * 64 + lane;
    const int p1 = p0 + 256;
    const int r0 = p0 >> 2, c0 = (p0 & 3) ^ ((r0 >> 1) & 3);
    const int r1 = p1 >> 2, c1 = (p1 & 3) ^ ((r1 >> 1) & 3);

    const bf16* srcA0 = A + (size_t)(m0 + r0) * K + c0 * 8;
    const bf16* srcA1 = A + (size_t)(m0 + r1) * K + c1 * 8;
    int nr0 = n0 + r0; if (nr0 >= N) nr0 = N - 1;
    int nr1 = n0 + r1; if (nr1 >= N) nr1 = N - 1;
    const bf16* srcB0 = W + (size_t)nr0 * K + c0 * 8;
    const bf16* srcB1 = W + (size_t)nr1 * K + c1 * 8;

    const int C4 = lane >> 4;
    const int fr = lane & 15;
    int aOff[4], bOff[4];
    #pragma unroll
    for (int i = 0; i < 4; ++i) {
        const int R = wm + i * 16 + fr;
        aOff[i] = R * 32 + ((C4 ^ ((R >> 1) & 3)) << 3);
    }
    #pragma unroll
    for (int j = 0; j < 4; ++j) {
        const int R = wn + j * 16 + fr;
        bOff[j] = R * 32 + ((C4 ^ ((R >> 1) & 3)) << 3);
    }

    f32x4 acc[4][4] = {};

    const int kb  = blockIdx.z * kchunk;
    const int nit = kchunk / 32;

    // prologue: stage tile 0 into buffer 0
    gll16(srcA0 + kb, &As[wv * 512]);
    gll16(srcA1 + kb, &As[(wv + 4) * 512]);
    gll16(srcB0 + kb, &Bs[wv * 512]);
    gll16(srcB1 + kb, &Bs[(wv + 4) * 512]);

    for (int it = 0; it < nit; ++it) {
        __syncthreads();                 // buf p ready; prior reads of buf q done
        const int p = it & 1;
        if (it + 1 < nit) {
            const int q  = p ^ 1;
            const int k1 = kb + (it + 1) * 32;
            gll16(srcA0 + k1, &As[q * 4096 + wv * 512]);
            gll16(srcA1 + k1, &As[q * 4096 + (wv + 4) * 512]);
            gll16(srcB0 + k1, &Bs[q * 4096 + wv * 512]);
            gll16(srcB1 + k1, &Bs[q * 4096 + (wv + 4) * 512]);
        }
        bf16x8 af[4], bfr[4];
        #pragma unroll
        for (int i = 0; i < 4; ++i) af[i]  = *(const bf16x8*)&As[p * 4096 + aOff[i]];
        #pragma unroll
        for (int j = 0; j < 4; ++j) bfr[j] = *(const bf16x8*)&Bs[p * 4096 + bOff[j]];
        #pragma unroll
        for (int i = 0; i < 4; ++i)
            #pragma unroll
            for (int j = 0; j < 4; ++j)
                acc[i][j] = __builtin_amdgcn_mfma_f32_16x16x32_bf16(af[i], bfr[j], acc[i][j], 0, 0, 0);
    }

    __syncthreads();   // all LDS reads done; smem free for epilogue repack

    const int rb = (lane >> 4) * 4;

    if constexpr (sizeof(TO) == 2) {
        // bf16 out: one pass, 128x128 bf16 = 32 KB
        bf16* cs = (bf16*)smem;
        #pragma unroll
        for (int i = 0; i < 4; ++i)
            #pragma unroll
            for (int j = 0; j < 4; ++j)
                #pragma unroll
                for (int r = 0; r < 4; ++r) {
                    const int m = wm + i * 16 + rb + r;
                    const int n = wn + j * 16 + fr;
                    float v = acc[i][j][r];
                    if (EPI == 1) {
                        v += bias[n0 + n];
                        // fast softplus via v_exp/v_log (bf16-out quantization
                        // dwarfs ~1ulp intrinsic error; libm was 42us, R1)
                        v = (v > 20.f) ? v : __logf(1.f + __expf(v));
                    }
                    const int key = (m >> 2) & 3;
                    cs[m * 128 + (n ^ ((key & 1) << 4) ^ ((key >> 1) << 5))] = sto<bf16>(v);
                }
        __syncthreads();
        TO* ob; int nc0; int ostr;
        if (split > 0) {
            if (n0 < split) { ob = out;  nc0 = n0;         }
            else            { ob = out2; nc0 = n0 - split; }
            ostr = split;
        } else { ob = out; nc0 = n0; ostr = N; }
        #pragma unroll
        for (int g8 = 0; g8 < 8; ++g8) {
            const int G = tid + 256 * g8;
            const int mrow = G >> 4;
            const int cg = G & 15;
            const int key = (mrow >> 2) & 3;
            const int nst = (cg * 8) ^ ((key & 1) << 4) ^ ((key >> 1) << 5);
            if (n0 + nst < N) {
                const uint4 val = *(const uint4*)&cs[mrow * 128 + cg * 8];
                *(uint4*)&ob[(size_t)(m0 + mrow) * ostr + nc0 + nst] = val;
            }
        }
    } else {
        // f32 out: two n-half passes of 128x64 f32 = 32 KB
        float* fs = (float*)smem;
        float* obase = SPLITK ? ((float*)out + (size_t)blockIdx.z * M * N) : (float*)out;
        #pragma unroll
        for (int ph = 0; ph < 2; ++ph) {
            __syncthreads();
            if ((wn >> 6) == ph) {       // the 2 waves owning this n-half write
                #pragma unroll
                for (int i = 0; i < 4; ++i)
                    #pragma unroll
                    for (int j = 0; j < 4; ++j)
                        #pragma unroll
                        for (int r = 0; r < 4; ++r) {
                            const int m = wm + i * 16 + rb + r;
                            const int qq = j * 16 + fr;
                            fs[m * 64 + (qq ^ (((m >> 2) & 1) << 4))] = acc[i][j][r];
                        }
            }
            __syncthreads();
            #pragma unroll
            for (int g8 = 0; g8 < 8; ++g8) {
                const int G = tid + 256 * g8;
                const int mrow = G >> 4;
                const int cg = G & 15;
                const int qst = (cg * 4) ^ (((mrow >> 2) & 1) << 4);
                const int n_g = 64 * ph + qst;
                if (n0 + n_g < N) {
                    const float4 val = *(const float4*)&fs[mrow * 64 + cg * 4];
                    *(float4*)&obase[(size_t)(m0 + mrow) * N + n0 + n_g] = val;
                }
            }
        }
    }
}

// sum 8 split-K partials of the bcx projection; emit xr (bf16, 4096x64)
// and B|C (f32, 4096x32).
__global__ __launch_bounds__(256)
void reduce_bcx(const float* __restrict__ P8, bf16* __restrict__ xr,
                float* __restrict__ BC)
{
    const int u = blockIdx.x * 256 + threadIdx.x;   // over MROWS*NBCX
    const int m = u / NBCX;
    const int n = u - m * NBCX;
    float s = 0.f;
    #pragma unroll
    for (int k = 0; k < 8; ++k) s += P8[(size_t)k * MROWS * NBCX + u];
    if (n < 64) xr[(size_t)m * 64 + n] = sto<bf16>(s);
    else        BC[(size_t)m * 32 + (n - 64)] = s;
}

// causal depthwise conv (d_conv=4) + bias + SiLU, 8 elems/thread, 16B ldst
__global__ __launch_bounds__(256)
void conv_silu(const bf16* __restrict__ x_in, const float* __restrict__ cw,
               const float* __restrict__ cb, bf16* __restrict__ x_conv)
{
    const size_t i8 = (size_t)(blockIdx.x * 256 + threadIdx.x) * 8;
    const int d = (int)(i8 & (DINNER - 1));
    const int t = (int)((i8 >> 11) & (LSEQ - 1));
    uint4 v[4];
    const uint4 z4 = make_uint4(0, 0, 0, 0);
    v[3] = *(const uint4*)(x_in + i8);
    v[2] = (t >= 1) ? *(const uint4*)(x_in + i8 - 1 * DINNER) : z4;
    v[1] = (t >= 2) ? *(const uint4*)(x_in + i8 - 2 * DINNER) : z4;
    v[0] = (t >= 3) ? *(const uint4*)(x_in + i8 - 3 * DINNER) : z4;
    const bf16* e0 = (const bf16*)&v[0];
    const bf16* e1 = (const bf16*)&v[1];
    const bf16* e2 = (const bf16*)&v[2];
    const bf16* e3 = (const bf16*)&v[3];
    bf16 ob[8];
    #pragma unroll
    for (int e = 0; e < 8; ++e) {
        const float4 w = *(const float4*)(cw + (size_t)(d + e) * 4);
        float a = cb[d + e];
        a = fmaf(w.x, cvt(e0[e]), a);
        a = fmaf(w.y, cvt(e1[e]), a);
        a = fmaf(w.z, cvt(e2[e]), a);
        a = fmaf(w.w, cvt(e3[e]), a);
        const float sig = 1.f / (1.f + __expf(-a));
        ob[e] = sto<bf16>(a * sig);
    }
    *(uint4*)(x_conv + i8) = *(const uint4*)ob;
}

// ---------------- chunked two-phase selective scan ----------------
// B/C rows in BC buffer: row stride 32 f32, B at +0, C at +16.
// 1 d per thread (R5's 2-d/thread spilled h/P/Af state past the VGPR
// budget -> scratch thrash, 10us -> 64us; TLP at 2048 waves is what
// hides the latency here).
__global__ __launch_bounds__(64)
void scan_phase_a(const bf16* __restrict__ x_conv, const bf16* __restrict__ dt,
                  const float* __restrict__ BC, const float* __restrict__ A_log,
                  float* __restrict__ hend, float* __restrict__ Pprod)
{
    const int lane = threadIdx.x;
    const int c = blockIdx.x;
    const int d = blockIdx.y * 64 + lane;
    const int b = blockIdx.z;

    float Af[DSTATE];
    #pragma unroll
    for (int s = 0; s < DSTATE; ++s) Af[s] = -__expf(A_log[d * DSTATE + s]);

    float h[DSTATE], P[DSTATE];
    #pragma unroll
    for (int s = 0; s < DSTATE; ++s) { h[s] = 0.f; P[s] = 1.f; }

    const size_t base = ((size_t)b * LSEQ + (size_t)c * CHUNK) * DINNER + d;
    const bf16* xp  = x_conv + base;
    const bf16* dtp = dt + base;
    const float* Bp = BC + ((size_t)b * LSEQ + (size_t)c * CHUNK) * 32;

    for (int t0 = 0; t0 < CHUNK; t0 += 4) {
        float xg[4], dtg[4];
        #pragma unroll
        for (int j = 0; j < 4; ++j) {
            xg[j]  = cvt(xp [(size_t)(t0 + j) * DINNER]);
            dtg[j] = cvt(dtp[(size_t)(t0 + j) * DINNER]);
        }
        #pragma unroll
        for (int j = 0; j < 4; ++j) {
            float Bv[DSTATE];
            const float* Br = Bp + (size_t)(t0 + j) * 32;
            *(float4*)(&Bv[0])  = *(const float4*)(Br + 0);
            *(float4*)(&Bv[4])  = *(const float4*)(Br + 4);
            *(float4*)(&Bv[8])  = *(const float4*)(Br + 8);
            *(float4*)(&Bv[12]) = *(const float4*)(Br + 12);
            const float dtv = dtg[j];
            const float dtx = dtv * xg[j];
            #pragma unroll
            for (int s = 0; s < DSTATE; ++s) {
                const float a = fmaf(dtv, Af[s], 1.0f);
                h[s] = fmaf(h[s], a, dtx * Bv[s]);
                P[s] *= a;
            }
        }
    }

    const size_t oidx = (((size_t)b * NCHUNK + c) * DINNER + d) * DSTATE;
    #pragma unroll
    for (int s = 0; s < DSTATE; ++s) {
        hend [oidx + s] = h[s];
        Pprod[oidx + s] = P[s];
    }
}

__global__ __launch_bounds__(256)
void scan_combine(float* __restrict__ hend, const float* __restrict__ Pprod)
{
    const int u = blockIdx.x * 256 + threadIdx.x;
    const int b = blockIdx.y;
    float h = 0.f;
    for (int c = 0; c < NCHUNK; ++c) {
        const size_t idx = ((size_t)b * NCHUNK + c) * DS_TOT + u;
        const float he = hend[idx];
        const float p  = Pprod[idx];
        hend[idx] = h;
        h = fmaf(p, h, he);
    }
}

__global__ __launch_bounds__(64)
void scan_phase_c(const bf16* __restrict__ x_conv, const bf16* __restrict__ dt,
                  const float* __restrict__ BC,
                  const float* __restrict__ A_log, const float* __restrict__ Dw,
                  const float* __restrict__ hin, bf16* __restrict__ zy)
{
    const int lane = threadIdx.x;
    const int c = blockIdx.x;
    const int d = blockIdx.y * 64 + lane;
    const int b = blockIdx.z;

    float Af[DSTATE];
    #pragma unroll
    for (int s = 0; s < DSTATE; ++s) Af[s] = -__expf(A_log[d * DSTATE + s]);
    const float Dv = Dw[d];

    float h[DSTATE];
    const size_t hidx = (((size_t)b * NCHUNK + c) * DINNER + d) * DSTATE;
    #pragma unroll
    for (int s = 0; s < DSTATE; ++s) h[s] = hin[hidx + s];

    const size_t base = ((size_t)b * LSEQ + (size_t)c * CHUNK) * DINNER + d;
    const bf16* xp  = x_conv + base;
    const bf16* dtp = dt + base;
    bf16*       zp  = zy + base;
    const float* Bp = BC + ((size_t)b * LSEQ + (size_t)c * CHUNK) * 32;
    const float* Cp = Bp + 16;

    for (int t0 = 0; t0 < CHUNK; t0 += 4) {
        float xg[4], dtg[4], zg[4];
        #pragma unroll
        for (int j = 0; j < 4; ++j) {
            xg[j]  = cvt(xp [(size_t)(t0 + j) * DINNER]);
            dtg[j] = cvt(dtp[(size_t)(t0 + j) * DINNER]);
            zg[j]  = cvt(zp [(size_t)(t0 + j) * DINNER]);
        }
        #pragma unroll
        for (int j = 0; j < 4; ++j) {
            float Bv[DSTATE], Cv[DSTATE];
            const float* Br = Bp + (size_t)(t0 + j) * 32;
            const float* Cr = Cp + (size_t)(t0 + j) * 32;
            *(float4*)(&Bv[0])  = *(const float4*)(Br + 0);
            *(float4*)(&Bv[4])  = *(const float4*)(Br + 4);
            *(float4*)(&Bv[8])  = *(const float4*)(Br + 8);
            *(float4*)(&Bv[12]) = *(const float4*)(Br + 12);
            *(float4*)(&Cv[0])  = *(const float4*)(Cr + 0);
            *(float4*)(&Cv[4])  = *(const float4*)(Cr + 4);
            *(float4*)(&Cv[8])  = *(const float4*)(Cr + 8);
            *(float4*)(&Cv[12]) = *(const float4*)(Cr + 12);
            const float dtv = dtg[j];
            const float dtx = dtv * xg[j];
            float y = 0.f;
            #pragma unroll
            for (int s = 0; s < DSTATE; ++s) {
                const float a = fmaf(dtv, Af[s], 1.0f);
                h[s] = fmaf(h[s], a, dtx * Bv[s]);
                y = fmaf(h[s], Cv[s], y);
            }
            const float zv = zg[j];
            const float sig = 1.f / (1.f + __expf(-zv));
            zp[(size_t)(t0 + j) * DINNER] = sto<bf16>(fmaf(Dv, xg[j], y) * (zv * sig));
        }
    }
}

extern "C" void kernel_launch(void* const* d_in, const int* in_sizes, int n_in,
                              void* d_out, int out_size, void* d_ws, size_t ws_size,
                              hipStream_t stream)
{
    const float* x          = (const float*)d_in[0];
    const float* in_proj_w  = (const float*)d_in[1];
    const float* conv_w     = (const float*)d_in[2];
    const float* conv_b     = (const float*)d_in[3];
    const float* A_log      = (const float*)d_in[4];
    const float* Dw         = (const float*)d_in[5];
    const float* dt_proj_w  = (const float*)d_in[6];
    const float* dt_proj_b  = (const float*)d_in[7];
    const float* x_proj_w   = (const float*)d_in[8];
    const float* B_proj_w   = (const float*)d_in[9];
    const float* C_proj_w   = (const float*)d_in[10];
    const float* out_proj_w = (const float*)d_in[11];
    float* out = (float*)d_out;

    // workspace (~93 MB, with aliasing) — identical to R9 layout
    const size_t MD = (size_t)MROWS * DINNER;
    bf16* buf0 = (bf16*)d_ws;                        // x_in -> P8 -> dt
    bf16* buf1 = buf0 + MD;                          // z -> y (in place)
    bf16* buf2 = buf1 + MD;                          // x_conv
    bf16* xbf  = buf2 + MD;                          // x bf16 (dead after K1)
    bf16* wbf1 = xbf  + (size_t)MROWS * DMODEL;      // in_proj bf16
    bf16* wbf2 = wbf1 + (size_t)2 * DINNER * DMODEL; // out_proj bf16
    bf16* wbc  = wbf2 + (size_t)DMODEL * DINNER;     // packed bcx weights bf16
    bf16* wdt  = wbc  + (size_t)NBCX * DINNER;       // dt_proj_w bf16
    float* hend = (float*)(wdt + (size_t)DINNER * DTRANK);
    float* Pp   = hend + (size_t)BSZ * NCHUNK * DS_TOT;
    // aliases over dead regions:
    bf16*  xr_bf = xbf;                              // 4096x64 bf16 (xbf dead after K1)
    float* BCbuf = (float*)(xbf + (size_t)MROWS * DTRANK); // 4096x32 f32
    float* P8 = (float*)buf0;  // 12.58 MB over buf0 (16.78): x_in dead after conv

    dim3 blk(256);
    const int na = MROWS * DMODEL;
    const int nb = 2 * DINNER * DMODEL;
    const int nc = DMODEL * DINNER;
    const int nd = DINNER * DTRANK;
    const int nbcx = NBCX * DINNER;

    // fused f32->bf16 converts + weight pack (8 elems/thread)
    cvt_all<<<(na + nb + nc + nd + nbcx) / 2048, blk, 0, stream>>>(
        x, in_proj_w, out_proj_w, dt_proj_w, x_proj_w, B_proj_w, C_proj_w,
        xbf, wbf1, wbf2, wdt, wbc, na, nb, nc, nd, nbcx);

    // K1: xz = x @ in_proj_w^T — 256^2 8-phase MFMA, split into x_in | z
    gemm256<<<dim3((MROWS / 256) * (2 * DINNER / 256)), dim3(512), 0, stream>>>(
        xbf, wbf1, buf0, buf1, 2 * DINNER, DMODEL, DINNER);

    // K2: causal depthwise conv + SiLU
    conv_silu<<<(MROWS * DINNER) / (256 * 8), blk, 0, stream>>>(buf0, conv_w, conv_b, buf2);

    // K3: fused xr|B|C projection, split-K=8, partials -> P8 (over dead x_in)
    gemm_mfma<float, 1, 0><<<dim3(1, MROWS / 128, 8), blk, 0, stream>>>(
        buf2, wbc, P8, (float*)nullptr, nullptr, MROWS, NBCX, DINNER, 0, DINNER / 8);

    // reduce partials -> xr (bf16) + B|C (f32)
    reduce_bcx<<<(MROWS * NBCX) / 256, blk, 0, stream>>>(P8, xr_bf, BCbuf);

    // K4: dt = softplus(xr @ dt_proj_w^T + b)  (MFMA, K=64) -> buf0 (over dead P8)
    gemm_mfma<bf16, 0, 1><<<dim3(DINNER / 128, MROWS / 128, 1), blk, 0, stream>>>(
        xr_bf, wdt, buf0, (bf16*)nullptr, dt_proj_b, MROWS, DINNER, DTRANK, 0, DTRANK);

    // K5: chunked two-phase selective scan (y over z in place in buf1)
    scan_phase_a<<<dim3(NCHUNK, DINNER / 64, BSZ), dim3(64), 0, stream>>>(
        buf2, buf0, BCbuf, A_log, hend, Pp);
    scan_combine<<<dim3(DS_TOT / 256, BSZ), dim3(256), 0, stream>>>(hend, Pp);
    scan_phase_c<<<dim3(NCHUNK, DINNER / 64, BSZ), dim3(64), 0, stream>>>(
        buf2, buf0, BCbuf, A_log, Dw, hend, buf1);

    // K6: out = y @ out_proj_w^T (MFMA dbuf) -> f32 d_out
    gemm_mfma<float, 0, 0><<<dim3(DMODEL / 128, MROWS / 128, 1), blk, 0, stream>>>(
        buf1, wbf2, out, (float*)nullptr, nullptr, MROWS, DMODEL, DINNER, 0, DINNER);
}

// Round 7
// 274.821 us; speedup vs baseline: 1.2031x; 1.0447x over previous
//
#include <hip/hip_runtime.h>
#include <hip/hip_bf16.h>
#include <math.h>

using bf16 = __hip_bfloat16;
typedef short bf16x8 __attribute__((ext_vector_type(8)));
typedef float f32x4  __attribute__((ext_vector_type(4)));

#define DMODEL 1024
#define DSTATE 16
#define DCONV  4
#define DINNER 2048
#define DTRANK 64
#define BSZ    2
#define LSEQ   2048
#define MROWS  (BSZ*LSEQ)   // 4096

#define NCHUNK 32
#define CHUNK  (LSEQ / NCHUNK)     // 64
#define DS_TOT (DINNER * DSTATE)   // 32768
#define NBCX   96                  // packed [x_proj(64) | B(16) | C(16)]

__device__ __forceinline__ float cvt(float v) { return v; }
__device__ __forceinline__ float cvt(bf16 v)  { return __bfloat162float(v); }

template<typename T> __device__ __forceinline__ T sto(float v);
template<> __device__ __forceinline__ float sto<float>(float v) { return v; }
template<> __device__ __forceinline__ bf16  sto<bf16>(float v)  { return __float2bfloat16(v); }

// async global->LDS 16B copy: HW writes lds_base(wave-uniform) + lane*16
__device__ __forceinline__ void gll16(const bf16* g, short* l)
{
    __builtin_amdgcn_global_load_lds(
        (const __attribute__((address_space(1))) unsigned int*)(const void*)g,
        (__attribute__((address_space(3))) unsigned int*)(void*)l,
        16, 0, 0);
}

// -- fused f32->bf16 convert: x | in_proj_w | out_proj_w | dt_proj_w | bcx --
// 8 elems/thread: 2x float4 in, one uint4 (16B) out.
__global__ __launch_bounds__(256)
void cvt_all(const float* __restrict__ a, const float* __restrict__ b,
             const float* __restrict__ c, const float* __restrict__ d,
             const float* __restrict__ xp, const float* __restrict__ Bp,
             const float* __restrict__ Cp,
             bf16* __restrict__ oa, bf16* __restrict__ ob, bf16* __restrict__ oc,
             bf16* __restrict__ od, bf16* __restrict__ obcx,
             int na, int nb, int nc, int nd, int nbcx)
{
    const int idx = (blockIdx.x * 256 + threadIdx.x) * 8;
    const float* src; bf16* dst; int off;
    if (idx < na)                      { src = a; dst = oa; off = idx; }
    else if (idx < na + nb)            { src = b; dst = ob; off = idx - na; }
    else if (idx < na + nb + nc)       { src = c; dst = oc; off = idx - na - nb; }
    else if (idx < na + nb + nc + nd)  { src = d; dst = od; off = idx - na - nb - nc; }
    else if (idx < na+nb+nc+nd+nbcx) {
        off = idx - na - nb - nc - nd;
        const int r = off >> 11, k = off & 2047;
        src = (r < 64) ? (xp + (size_t)r * 2048 + k)
            : (r < 80) ? (Bp + (size_t)(r - 64) * 2048 + k)
                       : (Cp + (size_t)(r - 80) * 2048 + k);
        src -= off;
        dst = obcx;
    } else return;
    const float4 v0 = *(const float4*)(src + off);
    const float4 v1 = *(const float4*)(src + off + 4);
    union { uint4 u; bf16 h[8]; } o;
    o.h[0] = sto<bf16>(v0.x); o.h[1] = sto<bf16>(v0.y);
    o.h[2] = sto<bf16>(v0.z); o.h[3] = sto<bf16>(v0.w);
    o.h[4] = sto<bf16>(v1.x); o.h[5] = sto<bf16>(v1.y);
    o.h[6] = sto<bf16>(v1.z); o.h[7] = sto<bf16>(v1.w);
    *(uint4*)(dst + off) = o.u;
}

// ===================== 256x256 8-phase MFMA GEMM (K1) ======================
// C[m,n] = sum_k A[m,k]*W[n,k], bf16 out split at column `split`.
// BM=BN=256, BK=64, 512 thr = 8 waves (2M x 4N), per-wave 128x64 out.
// LDS 128KB: A_b0 | A_b1 | B_b0 | B_b1, each 256x64 bf16 staged as two
// 128-row halves; tile t lives in buf t&1.
// Swizzle (T2): involution swz(o) = o ^ (((o>>7)&7)<<4) within each 16KB
// half (row = o>>7, 128B rows). global_load_lds dest stays LINEAR; source
// address and ds_read address both apply swz (rule #21).
// Schedule (T3+T4): per iteration (tiles 2i,2i+1) 8 phases; phase =
// {ds_read quadrant, stage 1 half-tile, [vmcnt(4) @ p4/p8], s_barrier,
//  lgkmcnt(0), setprio(1), 16 MFMA, setprio(0), s_barrier}.
// R6 counters: MfmaUtil 32% = pure-MFMA floor 13.9us of 43.3us; remainder
// is lockstep stall at 1 block/CU (128KB LDS). Structural; a 2-block/CU
// BK=32 variant is a new sync-template (race-screen required) — deferred.
#define BAR   __builtin_amdgcn_s_barrier()
#define LGK0  asm volatile("s_waitcnt lgkmcnt(0)" ::: "memory")
#define VM4   asm volatile("s_waitcnt vmcnt(4)" ::: "memory")
#define VM0   asm volatile("s_waitcnt vmcnt(0)" ::: "memory")
#define PRIO1 __builtin_amdgcn_s_setprio(1)
#define PRIO0 __builtin_amdgcn_s_setprio(0)

#define STAGE(PTR, SOFF, REGSH, T, H) \
  { const bf16* s_ = (PTR) + (SOFF) + (size_t)(H)*128*K + (size_t)(T)*64; \
    short* d_ = lds + (REGSH) + (H)*8192 + tid*8; \
    gll16(s_, d_); gll16(s_ + rstep, d_ + 4096); }

#define RD_A(BASE, MH) \
  { _Pragma("unroll") \
    for (int ii = 0; ii < 4; ++ii) { \
      const int fb_ = (BASE) + ((MH)*4 + ii) * 2048; \
      a_[ii][0] = *(const bf16x8*)(ldsB + (fb_ + kc0)); \
      a_[ii][1] = *(const bf16x8*)(ldsB + (fb_ + kc1)); } }

#define RD_B(BASE, NH, B_) \
  { _Pragma("unroll") \
    for (int jj = 0; jj < 2; ++jj) { \
      const int fb_ = (BASE) + ((NH)*2 + jj) * 2048; \
      B_[jj][0] = *(const bf16x8*)(ldsB + (fb_ + kc0)); \
      B_[jj][1] = *(const bf16x8*)(ldsB + (fb_ + kc1)); } }

#define MM(MH, NH, B_) \
  { _Pragma("unroll") \
    for (int ii = 0; ii < 4; ++ii) { \
      _Pragma("unroll") \
      for (int jj = 0; jj < 2; ++jj) { \
        f32x4& c_ = acc[(MH)*4 + ii][(NH)*2 + jj]; \
        c_ = __builtin_amdgcn_mfma_f32_16x16x32_bf16(a_[ii][0], B_[jj][0], c_, 0, 0, 0); \
        c_ = __builtin_amdgcn_mfma_f32_16x16x32_bf16(a_[ii][1], B_[jj][1], c_, 0, 0, 0); } } }

__global__ __launch_bounds__(512, 2)
void gemm256(const bf16* __restrict__ A, const bf16* __restrict__ W,
             bf16* __restrict__ out0, bf16* __restrict__ out1,
             int N, int K, int split)
{
    __shared__ __align__(16) short lds[65536];   // 128 KB

    const int tid  = threadIdx.x;
    const int lane = tid & 63;
    const int wv   = tid >> 6;
    const int wm_i = wv >> 2;      // 0..1
    const int wn_i = wv & 3;       // 0..3
    const int fr   = lane & 15;
    const int C4   = lane >> 4;

    // T1: bijective XCD-aware swizzle of the 1D grid
    int wg = blockIdx.x;
    { const int nwg = gridDim.x;
      const int q = nwg >> 3, r = nwg & 7, x = wg & 7, o = wg >> 3;
      wg = (x < r ? x * (q + 1) : r * (q + 1) + (x - r) * q) + o; }
    const int nbx = N >> 8;
    const int bx = wg % nbx, by = wg / nbx;
    const int m0 = by * 256, n0 = bx * 256;

    // staging per-thread constants (source pre-swizzle = same involution)
    const int lr  = tid >> 3;                                        // 0..63
    const int cbh = ((((tid & 7) << 4) ^ (((tid >> 3) & 7) << 4)) >> 1); // elems
    const size_t aso   = (size_t)(m0 + lr) * K + cbh;
    const size_t bso   = (size_t)(n0 + lr) * K + cbh;
    const size_t rstep = (size_t)64 * K;

    // ds_read per-lane constants (byte offsets, swz applied)
    const char* const ldsB = (const char*)lds;
    const int xk  = (fr & 7) << 4;
    const int kc0 = (C4 * 16) ^ xk;           // kk=0 slice
    const int kc1 = (64 + C4 * 16) ^ xk;      // kk=1 slice
    // region byte bases: A_b0=0, A_b1=32768, B_b0=65536, B_b1=98304
    const int aRB0 = 0     + wm_i * 16384 + fr * 128;
    const int aRB1 = 32768 + wm_i * 16384 + fr * 128;
    const int bRB0 = 65536 + (wn_i >> 1) * 16384 + (wn_i & 1) * 8192 + fr * 128;
    const int bRB1 = 98304 + (wn_i >> 1) * 16384 + (wn_i & 1) * 8192 + fr * 128;

    f32x4  acc[8][4] = {};
    bf16x8 a_[4][2], b0_[2][2], b1_[2][2];

    // prologue: A(0)->A_b0, B(0)->B_b0, B(1)->B_b1; drain; barrier
    STAGE(A, aso, 0,     0, 0); STAGE(A, aso, 0,     0, 1);
    STAGE(W, bso, 32768, 0, 0); STAGE(W, bso, 32768, 0, 1);
    STAGE(W, bso, 49152, 1, 0); STAGE(W, bso, 49152, 1, 1);
    VM0; BAR;

    const int NIT = K >> 7;          // 2 K-tiles (BK=64) per iteration
    for (int it = 0; it < NIT; ++it) {
        const int tA1 = 2 * it + 1;
        const int tN  = 2 * it + 2;
        const bool pf = (it + 1 < NIT);
        // p1: tile 2it quadrant (0,0)
        RD_A(aRB0, 0); RD_B(bRB0, 0, b0_);
        STAGE(A, aso, 16384, tA1, 0);
        BAR; LGK0; PRIO1; MM(0, 0, b0_); PRIO0; BAR;
        // p2: (0,1)
        RD_B(bRB0, 1, b1_);
        STAGE(A, aso, 16384, tA1, 1);
        BAR; LGK0; PRIO1; MM(0, 1, b1_); PRIO0; BAR;
        // p3: (1,0)
        RD_A(aRB0, 1);
        if (pf) STAGE(W, bso, 32768, tN, 0);
        BAR; LGK0; PRIO1; MM(1, 0, b0_); PRIO0; BAR;
        // p4: (1,1)  [counted vmcnt; full drain on last iter]
        if (pf) { STAGE(W, bso, 32768, tN, 1); VM4; } else { VM0; }
        BAR; LGK0; PRIO1; MM(1, 1, b1_); PRIO0; BAR;
        // p5: tile 2it+1 quadrant (0,0)
        RD_A(aRB1, 0); RD_B(bRB1, 0, b0_);
        if (pf) STAGE(A, aso, 0, tN, 0);
        BAR; LGK0; PRIO1; MM(0, 0, b0_); PRIO0; BAR;
        // p6: (0,1)
        RD_B(bRB1, 1, b1_);
        if (pf) STAGE(A, aso, 0, tN, 1);
        BAR; LGK0; PRIO1; MM(0, 1, b1_); PRIO0; BAR;
        // p7: (1,0)
        RD_A(aRB1, 1);
        if (pf) STAGE(W, bso, 49152, 2 * it + 3, 0);
        BAR; LGK0; PRIO1; MM(1, 0, b0_); PRIO0; BAR;
        // p8: (1,1)
        if (pf) { STAGE(W, bso, 49152, 2 * it + 3, 1); VM4; }
        BAR; LGK0; PRIO1; MM(1, 1, b1_); PRIO0; BAR;
    }

    // ---------- epilogue: repack through (dead) LDS, 16B stores ----------
    bf16* cs = (bf16*)lds;                      // 256x256 bf16 = 128KB
    #pragma unroll
    for (int i = 0; i < 8; ++i)
        #pragma unroll
        for (int j = 0; j < 4; ++j)
            #pragma unroll
            for (int r = 0; r < 4; ++r) {
                const int m = wm_i * 128 + i * 16 + C4 * 4 + r;
                const int n = wn_i * 64  + j * 16 + fr;
                cs[m * 256 + (n ^ ((m & 7) << 3))] = sto<bf16>(acc[i][j][r]);
            }
    __syncthreads();
    bf16* dst; int colb;
    if (n0 < split) { dst = out0; colb = n0; }
    else            { dst = out1; colb = n0 - split; }
    #pragma unroll
    for (int g = 0; g < 16; ++g) {
        const int G = tid + 512 * g;
        const int m = G >> 5;
        const int c = G & 31;
        const uint4 v = *(const uint4*)&cs[m * 256 + ((c * 8) ^ ((m & 7) << 3))];
        *(uint4*)&dst[(size_t)(m0 + m) * split + colb + c * 8] = v;
    }
}

// -------- MFMA GEMM: bf16 async-LDS dbuf staging + vectorized epilogue -----
// (kept for K3/K4/K6 — grids too small for 256^2 tiles)
template<typename TO, int SPLITK, int EPI>
__global__ __launch_bounds__(256)
void gemm_mfma(const bf16* __restrict__ A, const bf16* __restrict__ W,
               TO* __restrict__ out, TO* __restrict__ out2,
               const float* __restrict__ bias,
               int M, int N, int K, int split, int kchunk)
{
    __shared__ __align__(16) short smem[16384];   // 32 KB
    short* As = smem;            // [2][4096]
    short* Bs = smem + 8192;     // [2][4096]

    const int tid  = threadIdx.x;
    const int lane = tid & 63;
    const int wv   = tid >> 6;
    const int wm = (wv & 1) * 64;
    const int wn = (wv >> 1) * 64;
    const int m0 = blockIdx.y * 128;
    const int n0 = blockIdx.x * 128;

    const int p0 = wv * 64 + lane;
    const int p1 = p0 + 256;
    const int r0 = p0 >> 2, c0 = (p0 & 3) ^ ((r0 >> 1) & 3);
    const int r1 = p1 >> 2, c1 = (p1 & 3) ^ ((r1 >> 1) & 3);

    const bf16* srcA0 = A + (size_t)(m0 + r0) * K + c0 * 8;
    const bf16* srcA1 = A + (size_t)(m0 + r1) * K + c1 * 8;
    int nr0 = n0 + r0; if (nr0 >= N) nr0 = N - 1;
    int nr1 = n0 + r1; if (nr1 >= N) nr1 = N - 1;
    const bf16* srcB0 = W + (size_t)nr0 * K + c0 * 8;
    const bf16* srcB1 = W + (size_t)nr1 * K + c1 * 8;

    const int C4 = lane >> 4;
    const int fr = lane & 15;
    int aOff[4], bOff[4];
    #pragma unroll
    for (int i = 0; i < 4; ++i) {
        const int R = wm + i * 16 + fr;
        aOff[i] = R * 32 + ((C4 ^ ((R >> 1) & 3)) << 3);
    }
    #pragma unroll
    for (int j = 0; j < 4; ++j) {
        const int R = wn + j * 16 + fr;
        bOff[j] = R * 32 + ((C4 ^ ((R >> 1) & 3)) << 3);
    }

    f32x4 acc[4][4] = {};

    const int kb  = blockIdx.z * kchunk;
    const int nit = kchunk / 32;

    // prologue: stage tile 0 into buffer 0
    gll16(srcA0 + kb, &As[wv * 512]);
    gll16(srcA1 + kb, &As[(wv + 4) * 512]);
    gll16(srcB0 + kb, &Bs[wv * 512]);
    gll16(srcB1 + kb, &Bs[(wv + 4) * 512]);

    for (int it = 0; it < nit; ++it) {
        __syncthreads();                 // buf p ready; prior reads of buf q done
        const int p = it & 1;
        if (it + 1 < nit) {
            const int q  = p ^ 1;
            const int k1 = kb + (it + 1) * 32;
            gll16(srcA0 + k1, &As[q * 4096 + wv * 512]);
            gll16(srcA1 + k1, &As[q * 4096 + (wv + 4) * 512]);
            gll16(srcB0 + k1, &Bs[q * 4096 + wv * 512]);
            gll16(srcB1 + k1, &Bs[q * 4096 + (wv + 4) * 512]);
        }
        bf16x8 af[4], bfr[4];
        #pragma unroll
        for (int i = 0; i < 4; ++i) af[i]  = *(const bf16x8*)&As[p * 4096 + aOff[i]];
        #pragma unroll
        for (int j = 0; j < 4; ++j) bfr[j] = *(const bf16x8*)&Bs[p * 4096 + bOff[j]];
        #pragma unroll
        for (int i = 0; i < 4; ++i)
            #pragma unroll
            for (int j = 0; j < 4; ++j)
                acc[i][j] = __builtin_amdgcn_mfma_f32_16x16x32_bf16(af[i], bfr[j], acc[i][j], 0, 0, 0);
    }

    __syncthreads();   // all LDS reads done; smem free for epilogue repack

    const int rb = (lane >> 4) * 4;

    if constexpr (sizeof(TO) == 2) {
        // bf16 out: one pass, 128x128 bf16 = 32 KB
        bf16* cs = (bf16*)smem;
        #pragma unroll
        for (int i = 0; i < 4; ++i)
            #pragma unroll
            for (int j = 0; j < 4; ++j)
                #pragma unroll
                for (int r = 0; r < 4; ++r) {
                    const int m = wm + i * 16 + rb + r;
                    const int n = wn + j * 16 + fr;
                    float v = acc[i][j][r];
                    if (EPI == 1) {
                        v += bias[n0 + n];
                        // fast softplus via v_exp/v_log (bf16-out quantization
                        // dwarfs ~1ulp intrinsic error; libm was 42us, R1)
                        v = (v > 20.f) ? v : __logf(1.f + __expf(v));
                    }
                    const int key = (m >> 2) & 3;
                    cs[m * 128 + (n ^ ((key & 1) << 4) ^ ((key >> 1) << 5))] = sto<bf16>(v);
                }
        __syncthreads();
        TO* ob; int nc0; int ostr;
        if (split > 0) {
            if (n0 < split) { ob = out;  nc0 = n0;         }
            else            { ob = out2; nc0 = n0 - split; }
            ostr = split;
        } else { ob = out; nc0 = n0; ostr = N; }
        #pragma unroll
        for (int g8 = 0; g8 < 8; ++g8) {
            const int G = tid + 256 * g8;
            const int mrow = G >> 4;
            const int cg = G & 15;
            const int key = (mrow >> 2) & 3;
            const int nst = (cg * 8) ^ ((key & 1) << 4) ^ ((key >> 1) << 5);
            if (n0 + nst < N) {
                const uint4 val = *(const uint4*)&cs[mrow * 128 + cg * 8];
                *(uint4*)&ob[(size_t)(m0 + mrow) * ostr + nc0 + nst] = val;
            }
        }
    } else {
        // f32 out: two n-half passes of 128x64 f32 = 32 KB
        float* fs = (float*)smem;
        float* obase = SPLITK ? ((float*)out + (size_t)blockIdx.z * M * N) : (float*)out;
        #pragma unroll
        for (int ph = 0; ph < 2; ++ph) {
            __syncthreads();
            if ((wn >> 6) == ph) {       // the 2 waves owning this n-half write
                #pragma unroll
                for (int i = 0; i < 4; ++i)
                    #pragma unroll
                    for (int j = 0; j < 4; ++j)
                        #pragma unroll
                        for (int r = 0; r < 4; ++r) {
                            const int m = wm + i * 16 + rb + r;
                            const int qq = j * 16 + fr;
                            fs[m * 64 + (qq ^ (((m >> 2) & 1) << 4))] = acc[i][j][r];
                        }
            }
            __syncthreads();
            #pragma unroll
            for (int g8 = 0; g8 < 8; ++g8) {
                const int G = tid + 256 * g8;
                const int mrow = G >> 4;
                const int cg = G & 15;
                const int qst = (cg * 4) ^ (((mrow >> 2) & 1) << 4);
                const int n_g = 64 * ph + qst;
                if (n0 + n_g < N) {
                    const float4 val = *(const float4*)&fs[mrow * 64 + cg * 4];
                    *(float4*)&obase[(size_t)(m0 + mrow) * N + n0 + n_g] = val;
                }
            }
        }
    }
}

// sum 8 split-K partials of the bcx projection; emit xr (bf16, 4096x64)
// and B|C (f32, 4096x32).
__global__ __launch_bounds__(256)
void reduce_bcx(const float* __restrict__ P8, bf16* __restrict__ xr,
                float* __restrict__ BC)
{
    const int u = blockIdx.x * 256 + threadIdx.x;   // over MROWS*NBCX
    const int m = u / NBCX;
    const int n = u - m * NBCX;
    float s = 0.f;
    #pragma unroll
    for (int k = 0; k < 8; ++k) s += P8[(size_t)k * MROWS * NBCX + u];
    if (n < 64) xr[(size_t)m * 64 + n] = sto<bf16>(s);
    else        BC[(size_t)m * 32 + (n - 64)] = s;
}

// causal depthwise conv (d_conv=4) + bias + SiLU.
// R7: sliding-window — each thread produces 8 consecutive t's for its 8-d
// group from an 11-row register window. Read amplification 4x -> 1.4x
// (67 -> 23 MB); weight/bias loads amortize 8x. Block = 256 thr covers all
// 2048 d's of one 8-t group; grid = MROWS/8 = 512 blocks. 2048%8==0 so
// t-groups never cross the batch boundary; t<0 rows zero-padded.
__global__ __launch_bounds__(256)
void conv_silu(const bf16* __restrict__ x_in, const float* __restrict__ cw,
               const float* __restrict__ cb, bf16* __restrict__ x_conv)
{
    const int tg = blockIdx.x;            // 512 t-groups of 8
    const int b  = tg >> 8;               // 256 groups per batch
    const int t0 = (tg & 255) << 3;
    const int d  = threadIdx.x * 8;
    const size_t rowbase = ((size_t)b * LSEQ + t0) * DINNER + d;

    uint4 v[11];
    const uint4 z4 = make_uint4(0, 0, 0, 0);
    #pragma unroll
    for (int r = 0; r < 11; ++r) {
        const int t = t0 + r - 3;
        v[r] = (t >= 0) ? *(const uint4*)(x_in + rowbase + (size_t)(r - 3) * DINNER) : z4;
    }
    float4 wq[8]; float bq[8];
    #pragma unroll
    for (int e = 0; e < 8; ++e) {
        wq[e] = *(const float4*)(cw + (size_t)(d + e) * 4);
        bq[e] = cb[d + e];
    }
    #pragma unroll
    for (int r = 0; r < 8; ++r) {
        const bf16* e0 = (const bf16*)&v[r];
        const bf16* e1 = (const bf16*)&v[r + 1];
        const bf16* e2 = (const bf16*)&v[r + 2];
        const bf16* e3 = (const bf16*)&v[r + 3];
        bf16 ob[8];
        #pragma unroll
        for (int e = 0; e < 8; ++e) {
            float a = bq[e];
            a = fmaf(wq[e].x, cvt(e0[e]), a);
            a = fmaf(wq[e].y, cvt(e1[e]), a);
            a = fmaf(wq[e].z, cvt(e2[e]), a);
            a = fmaf(wq[e].w, cvt(e3[e]), a);
            const float sig = 1.f / (1.f + __expf(-a));
            ob[e] = sto<bf16>(a * sig);
        }
        *(uint4*)(x_conv + rowbase + (size_t)r * DINNER) = *(const uint4*)ob;
    }
}

// ---------------- chunked two-phase selective scan ----------------
// B/C rows in BC buffer: row stride 32 f32, B at +0, C at +16.
// 1 d per thread (R5's 2-d/thread spilled h/P/Af state past the VGPR
// budget -> scratch thrash, 10us -> 64us; TLP at 2048 waves is what
// hides the latency here).
__global__ __launch_bounds__(64)
void scan_phase_a(const bf16* __restrict__ x_conv, const bf16* __restrict__ dt,
                  const float* __restrict__ BC, const float* __restrict__ A_log,
                  float* __restrict__ hend, float* __restrict__ Pprod)
{
    const int lane = threadIdx.x;
    const int c = blockIdx.x;
    const int d = blockIdx.y * 64 + lane;
    const int b = blockIdx.z;

    float Af[DSTATE];
    #pragma unroll
    for (int s = 0; s < DSTATE; ++s) Af[s] = -__expf(A_log[d * DSTATE + s]);

    float h[DSTATE], P[DSTATE];
    #pragma unroll
    for (int s = 0; s < DSTATE; ++s) { h[s] = 0.f; P[s] = 1.f; }

    const size_t base = ((size_t)b * LSEQ + (size_t)c * CHUNK) * DINNER + d;
    const bf16* xp  = x_conv + base;
    const bf16* dtp = dt + base;
    const float* Bp = BC + ((size_t)b * LSEQ + (size_t)c * CHUNK) * 32;

    for (int t0 = 0; t0 < CHUNK; t0 += 4) {
        float xg[4], dtg[4];
        #pragma unroll
        for (int j = 0; j < 4; ++j) {
            xg[j]  = cvt(xp [(size_t)(t0 + j) * DINNER]);
            dtg[j] = cvt(dtp[(size_t)(t0 + j) * DINNER]);
        }
        #pragma unroll
        for (int j = 0; j < 4; ++j) {
            float Bv[DSTATE];
            const float* Br = Bp + (size_t)(t0 + j) * 32;
            *(float4*)(&Bv[0])  = *(const float4*)(Br + 0);
            *(float4*)(&Bv[4])  = *(const float4*)(Br + 4);
            *(float4*)(&Bv[8])  = *(const float4*)(Br + 8);
            *(float4*)(&Bv[12]) = *(const float4*)(Br + 12);
            const float dtv = dtg[j];
            const float dtx = dtv * xg[j];
            #pragma unroll
            for (int s = 0; s < DSTATE; ++s) {
                const float a = fmaf(dtv, Af[s], 1.0f);
                h[s] = fmaf(h[s], a, dtx * Bv[s]);
                P[s] *= a;
            }
        }
    }

    const size_t oidx = (((size_t)b * NCHUNK + c) * DINNER + d) * DSTATE;
    #pragma unroll
    for (int s = 0; s < DSTATE; ++s) {
        hend [oidx + s] = h[s];
        Pprod[oidx + s] = P[s];
    }
}

__global__ __launch_bounds__(256)
void scan_combine(float* __restrict__ hend, const float* __restrict__ Pprod)
{
    const int u = blockIdx.x * 256 + threadIdx.x;
    const int b = blockIdx.y;
    float h = 0.f;
    for (int c = 0; c < NCHUNK; ++c) {
        const size_t idx = ((size_t)b * NCHUNK + c) * DS_TOT + u;
        const float he = hend[idx];
        const float p  = Pprod[idx];
        hend[idx] = h;
        h = fmaf(p, h, he);
    }
}

__global__ __launch_bounds__(64)
void scan_phase_c(const bf16* __restrict__ x_conv, const bf16* __restrict__ dt,
                  const float* __restrict__ BC,
                  const float* __restrict__ A_log, const float* __restrict__ Dw,
                  const float* __restrict__ hin, bf16* __restrict__ zy)
{
    const int lane = threadIdx.x;
    const int c = blockIdx.x;
    const int d = blockIdx.y * 64 + lane;
    const int b = blockIdx.z;

    float Af[DSTATE];
    #pragma unroll
    for (int s = 0; s < DSTATE; ++s) Af[s] = -__expf(A_log[d * DSTATE + s]);
    const float Dv = Dw[d];

    float h[DSTATE];
    const size_t hidx = (((size_t)b * NCHUNK + c) * DINNER + d) * DSTATE;
    #pragma unroll
    for (int s = 0; s < DSTATE; ++s) h[s] = hin[hidx + s];

    const size_t base = ((size_t)b * LSEQ + (size_t)c * CHUNK) * DINNER + d;
    const bf16* xp  = x_conv + base;
    const bf16* dtp = dt + base;
    bf16*       zp  = zy + base;
    const float* Bp = BC + ((size_t)b * LSEQ + (size_t)c * CHUNK) * 32;
    const float* Cp = Bp + 16;

    for (int t0 = 0; t0 < CHUNK; t0 += 4) {
        float xg[4], dtg[4], zg[4];
        #pragma unroll
        for (int j = 0; j < 4; ++j) {
            xg[j]  = cvt(xp [(size_t)(t0 + j) * DINNER]);
            dtg[j] = cvt(dtp[(size_t)(t0 + j) * DINNER]);
            zg[j]  = cvt(zp [(size_t)(t0 + j) * DINNER]);
        }
        #pragma unroll
        for (int j = 0; j < 4; ++j) {
            float Bv[DSTATE], Cv[DSTATE];
            const float* Br = Bp + (size_t)(t0 + j) * 32;
            const float* Cr = Cp + (size_t)(t0 + j) * 32;
            *(float4*)(&Bv[0])  = *(const float4*)(Br + 0);
            *(float4*)(&Bv[4])  = *(const float4*)(Br + 4);
            *(float4*)(&Bv[8])  = *(const float4*)(Br + 8);
            *(float4*)(&Bv[12]) = *(const float4*)(Br + 12);
            *(float4*)(&Cv[0])  = *(const float4*)(Cr + 0);
            *(float4*)(&Cv[4])  = *(const float4*)(Cr + 4);
            *(float4*)(&Cv[8])  = *(const float4*)(Cr + 8);
            *(float4*)(&Cv[12]) = *(const float4*)(Cr + 12);
            const float dtv = dtg[j];
            const float dtx = dtv * xg[j];
            float y = 0.f;
            #pragma unroll
            for (int s = 0; s < DSTATE; ++s) {
                const float a = fmaf(dtv, Af[s], 1.0f);
                h[s] = fmaf(h[s], a, dtx * Bv[s]);
                y = fmaf(h[s], Cv[s], y);
            }
            const float zv = zg[j];
            const float sig = 1.f / (1.f + __expf(-zv));
            zp[(size_t)(t0 + j) * DINNER] = sto<bf16>(fmaf(Dv, xg[j], y) * (zv * sig));
        }
    }
}

extern "C" void kernel_launch(void* const* d_in, const int* in_sizes, int n_in,
                              void* d_out, int out_size, void* d_ws, size_t ws_size,
                              hipStream_t stream)
{
    const float* x          = (const float*)d_in[0];
    const float* in_proj_w  = (const float*)d_in[1];
    const float* conv_w     = (const float*)d_in[2];
    const float* conv_b     = (const float*)d_in[3];
    const float* A_log      = (const float*)d_in[4];
    const float* Dw         = (const float*)d_in[5];
    const float* dt_proj_w  = (const float*)d_in[6];
    const float* dt_proj_b  = (const float*)d_in[7];
    const float* x_proj_w   = (const float*)d_in[8];
    const float* B_proj_w   = (const float*)d_in[9];
    const float* C_proj_w   = (const float*)d_in[10];
    const float* out_proj_w = (const float*)d_in[11];
    float* out = (float*)d_out;

    // workspace (~93 MB, with aliasing) — identical to R9 layout
    const size_t MD = (size_t)MROWS * DINNER;
    bf16* buf0 = (bf16*)d_ws;                        // x_in -> P8 -> dt
    bf16* buf1 = buf0 + MD;                          // z -> y (in place)
    bf16* buf2 = buf1 + MD;                          // x_conv
    bf16* xbf  = buf2 + MD;                          // x bf16 (dead after K1)
    bf16* wbf1 = xbf  + (size_t)MROWS * DMODEL;      // in_proj bf16
    bf16* wbf2 = wbf1 + (size_t)2 * DINNER * DMODEL; // out_proj bf16
    bf16* wbc  = wbf2 + (size_t)DMODEL * DINNER;     // packed bcx weights bf16
    bf16* wdt  = wbc  + (size_t)NBCX * DINNER;       // dt_proj_w bf16
    float* hend = (float*)(wdt + (size_t)DINNER * DTRANK);
    float* Pp   = hend + (size_t)BSZ * NCHUNK * DS_TOT;
    // aliases over dead regions:
    bf16*  xr_bf = xbf;                              // 4096x64 bf16 (xbf dead after K1)
    float* BCbuf = (float*)(xbf + (size_t)MROWS * DTRANK); // 4096x32 f32
    float* P8 = (float*)buf0;  // 12.58 MB over buf0 (16.78): x_in dead after conv

    dim3 blk(256);
    const int na = MROWS * DMODEL;
    const int nb = 2 * DINNER * DMODEL;
    const int nc = DMODEL * DINNER;
    const int nd = DINNER * DTRANK;
    const int nbcx = NBCX * DINNER;

    // fused f32->bf16 converts + weight pack (8 elems/thread)
    cvt_all<<<(na + nb + nc + nd + nbcx) / 2048, blk, 0, stream>>>(
        x, in_proj_w, out_proj_w, dt_proj_w, x_proj_w, B_proj_w, C_proj_w,
        xbf, wbf1, wbf2, wdt, wbc, na, nb, nc, nd, nbcx);

    // K1: xz = x @ in_proj_w^T — 256^2 8-phase MFMA, split into x_in | z
    gemm256<<<dim3((MROWS / 256) * (2 * DINNER / 256)), dim3(512), 0, stream>>>(
        xbf, wbf1, buf0, buf1, 2 * DINNER, DMODEL, DINNER);

    // K2: causal depthwise conv + SiLU (sliding window, 8 t's/thread)
    conv_silu<<<MROWS / 8, blk, 0, stream>>>(buf0, conv_w, conv_b, buf2);

    // K3: fused xr|B|C projection, split-K=8, partials -> P8 (over dead x_in)
    gemm_mfma<float, 1, 0><<<dim3(1, MROWS / 128, 8), blk, 0, stream>>>(
        buf2, wbc, P8, (float*)nullptr, nullptr, MROWS, NBCX, DINNER, 0, DINNER / 8);

    // reduce partials -> xr (bf16) + B|C (f32)
    reduce_bcx<<<(MROWS * NBCX) / 256, blk, 0, stream>>>(P8, xr_bf, BCbuf);

    // K4: dt = softplus(xr @ dt_proj_w^T + b)  (MFMA, K=64) -> buf0 (over dead P8)
    gemm_mfma<bf16, 0, 1><<<dim3(DINNER / 128, MROWS / 128, 1), blk, 0, stream>>>(
        xr_bf, wdt, buf0, (bf16*)nullptr, dt_proj_b, MROWS, DINNER, DTRANK, 0, DTRANK);

    // K5: chunked two-phase selective scan (y over z in place in buf1)
    scan_phase_a<<<dim3(NCHUNK, DINNER / 64, BSZ), dim3(64), 0, stream>>>(
        buf2, buf0, BCbuf, A_log, hend, Pp);
    scan_combine<<<dim3(DS_TOT / 256, BSZ), dim3(256), 0, stream>>>(hend, Pp);
    scan_phase_c<<<dim3(NCHUNK, DINNER / 64, BSZ), dim3(64), 0, stream>>>(
        buf2, buf0, BCbuf, A_log, Dw, hend, buf1);

    // K6: out = y @ out_proj_w^T (MFMA dbuf) -> f32 d_out
    gemm_mfma<float, 0, 0><<<dim3(DMODEL / 128, MROWS / 128, 1), blk, 0, stream>>>(
        buf1, wbf2, out, (float*)nullptr, nullptr, MROWS, DMODEL, DINNER, 0, DINNER);
}

// Round 8
// 274.611 us; speedup vs baseline: 1.2040x; 1.0008x over previous
//
#include <hip/hip_runtime.h>
#include <hip/hip_bf16.h>
#include <math.h>

using bf16 = __hip_bfloat16;
typedef short bf16x8 __attribute__((ext_vector_type(8)));
typedef float f32x4  __attribute__((ext_vector_type(4)));

#define DMODEL 1024
#define DSTATE 16
#define DCONV  4
#define DINNER 2048
#define DTRANK 64
#define BSZ    2
#define LSEQ   2048
#define MROWS  (BSZ*LSEQ)   // 4096

#define NCHUNK 32
#define CHUNK  (LSEQ / NCHUNK)     // 64
#define DS_TOT (DINNER * DSTATE)   // 32768
#define NBCX   96                  // packed [x_proj(64) | B(16) | C(16)]

__device__ __forceinline__ float cvt(float v) { return v; }
__device__ __forceinline__ float cvt(bf16 v)  { return __bfloat162float(v); }

template<typename T> __device__ __forceinline__ T sto(float v);
template<> __device__ __forceinline__ float sto<float>(float v) { return v; }
template<> __device__ __forceinline__ bf16  sto<bf16>(float v)  { return __float2bfloat16(v); }

// async global->LDS 16B copy: HW writes lds_base(wave-uniform) + lane*16
__device__ __forceinline__ void gll16(const bf16* g, short* l)
{
    __builtin_amdgcn_global_load_lds(
        (const __attribute__((address_space(1))) unsigned int*)(const void*)g,
        (__attribute__((address_space(3))) unsigned int*)(void*)l,
        16, 0, 0);
}

// -- fused f32->bf16 convert: x | in_proj_w | out_proj_w | dt_proj_w | bcx --
// 8 elems/thread: 2x float4 in, one uint4 (16B) out.
__global__ __launch_bounds__(256)
void cvt_all(const float* __restrict__ a, const float* __restrict__ b,
             const float* __restrict__ c, const float* __restrict__ d,
             const float* __restrict__ xp, const float* __restrict__ Bp,
             const float* __restrict__ Cp,
             bf16* __restrict__ oa, bf16* __restrict__ ob, bf16* __restrict__ oc,
             bf16* __restrict__ od, bf16* __restrict__ obcx,
             int na, int nb, int nc, int nd, int nbcx)
{
    const int idx = (blockIdx.x * 256 + threadIdx.x) * 8;
    const float* src; bf16* dst; int off;
    if (idx < na)                      { src = a; dst = oa; off = idx; }
    else if (idx < na + nb)            { src = b; dst = ob; off = idx - na; }
    else if (idx < na + nb + nc)       { src = c; dst = oc; off = idx - na - nb; }
    else if (idx < na + nb + nc + nd)  { src = d; dst = od; off = idx - na - nb - nc; }
    else if (idx < na+nb+nc+nd+nbcx) {
        off = idx - na - nb - nc - nd;
        const int r = off >> 11, k = off & 2047;
        src = (r < 64) ? (xp + (size_t)r * 2048 + k)
            : (r < 80) ? (Bp + (size_t)(r - 64) * 2048 + k)
                       : (Cp + (size_t)(r - 80) * 2048 + k);
        src -= off;
        dst = obcx;
    } else return;
    const float4 v0 = *(const float4*)(src + off);
    const float4 v1 = *(const float4*)(src + off + 4);
    union { uint4 u; bf16 h[8]; } o;
    o.h[0] = sto<bf16>(v0.x); o.h[1] = sto<bf16>(v0.y);
    o.h[2] = sto<bf16>(v0.z); o.h[3] = sto<bf16>(v0.w);
    o.h[4] = sto<bf16>(v1.x); o.h[5] = sto<bf16>(v1.y);
    o.h[6] = sto<bf16>(v1.z); o.h[7] = sto<bf16>(v1.w);
    *(uint4*)(dst + off) = o.u;
}

// ===================== 256x256 8-phase MFMA GEMM (K1) ======================
// C[m,n] = sum_k A[m,k]*W[n,k], bf16 out split at column `split`.
// BM=BN=256, BK=64, 512 thr = 8 waves (2M x 4N), per-wave 128x64 out.
// LDS 128KB: A_b0 | A_b1 | B_b0 | B_b1, each 256x64 bf16 staged as two
// 128-row halves; tile t lives in buf t&1.
// Swizzle (T2): involution swz(o) = o ^ (((o>>7)&7)<<4) within each 16KB
// half (row = o>>7, 128B rows). global_load_lds dest stays LINEAR; source
// address and ds_read address both apply swz (rule #21).
// Schedule (T3+T4): per iteration (tiles 2i,2i+1) 8 phases; phase =
// {ds_read quadrant, stage 1 half-tile, [vmcnt(4) @ p4/p8], s_barrier,
//  setprio(1), 16 MFMA, setprio(0), s_barrier}.
// R8: per-phase blanket lgkmcnt(0) REMOVED — ds_reads are compiler-visible
// loads, so hipcc emits minimal per-use counted lgkmcnt; first MFMA starts
// after its own 2 operand reads instead of all 12. Cross-wave staging
// visibility is carried entirely by vmcnt (VM4/VM0 kept, "memory" clobber
// blocks load motion across them) + the barriers; lgkm never protected it.
#define BAR   __builtin_amdgcn_s_barrier()
#define VM4   asm volatile("s_waitcnt vmcnt(4)" ::: "memory")
#define VM0   asm volatile("s_waitcnt vmcnt(0)" ::: "memory")
#define PRIO1 __builtin_amdgcn_s_setprio(1)
#define PRIO0 __builtin_amdgcn_s_setprio(0)

#define STAGE(PTR, SOFF, REGSH, T, H) \
  { const bf16* s_ = (PTR) + (SOFF) + (size_t)(H)*128*K + (size_t)(T)*64; \
    short* d_ = lds + (REGSH) + (H)*8192 + tid*8; \
    gll16(s_, d_); gll16(s_ + rstep, d_ + 4096); }

#define RD_A(BASE, MH) \
  { _Pragma("unroll") \
    for (int ii = 0; ii < 4; ++ii) { \
      const int fb_ = (BASE) + ((MH)*4 + ii) * 2048; \
      a_[ii][0] = *(const bf16x8*)(ldsB + (fb_ + kc0)); \
      a_[ii][1] = *(const bf16x8*)(ldsB + (fb_ + kc1)); } }

#define RD_B(BASE, NH, B_) \
  { _Pragma("unroll") \
    for (int jj = 0; jj < 2; ++jj) { \
      const int fb_ = (BASE) + ((NH)*2 + jj) * 2048; \
      B_[jj][0] = *(const bf16x8*)(ldsB + (fb_ + kc0)); \
      B_[jj][1] = *(const bf16x8*)(ldsB + (fb_ + kc1)); } }

#define MM(MH, NH, B_) \
  { _Pragma("unroll") \
    for (int ii = 0; ii < 4; ++ii) { \
      _Pragma("unroll") \
      for (int jj = 0; jj < 2; ++jj) { \
        f32x4& c_ = acc[(MH)*4 + ii][(NH)*2 + jj]; \
        c_ = __builtin_amdgcn_mfma_f32_16x16x32_bf16(a_[ii][0], B_[jj][0], c_, 0, 0, 0); \
        c_ = __builtin_amdgcn_mfma_f32_16x16x32_bf16(a_[ii][1], B_[jj][1], c_, 0, 0, 0); } } }

__global__ __launch_bounds__(512, 2)
void gemm256(const bf16* __restrict__ A, const bf16* __restrict__ W,
             bf16* __restrict__ out0, bf16* __restrict__ out1,
             int N, int K, int split)
{
    __shared__ __align__(16) short lds[65536];   // 128 KB

    const int tid  = threadIdx.x;
    const int lane = tid & 63;
    const int wv   = tid >> 6;
    const int wm_i = wv >> 2;      // 0..1
    const int wn_i = wv & 3;       // 0..3
    const int fr   = lane & 15;
    const int C4   = lane >> 4;

    // T1: bijective XCD-aware swizzle of the 1D grid
    int wg = blockIdx.x;
    { const int nwg = gridDim.x;
      const int q = nwg >> 3, r = nwg & 7, x = wg & 7, o = wg >> 3;
      wg = (x < r ? x * (q + 1) : r * (q + 1) + (x - r) * q) + o; }
    const int nbx = N >> 8;
    const int bx = wg % nbx, by = wg / nbx;
    const int m0 = by * 256, n0 = bx * 256;

    // staging per-thread constants (source pre-swizzle = same involution)
    const int lr  = tid >> 3;                                        // 0..63
    const int cbh = ((((tid & 7) << 4) ^ (((tid >> 3) & 7) << 4)) >> 1); // elems
    const size_t aso   = (size_t)(m0 + lr) * K + cbh;
    const size_t bso   = (size_t)(n0 + lr) * K + cbh;
    const size_t rstep = (size_t)64 * K;

    // ds_read per-lane constants (byte offsets, swz applied)
    const char* const ldsB = (const char*)lds;
    const int xk  = (fr & 7) << 4;
    const int kc0 = (C4 * 16) ^ xk;           // kk=0 slice
    const int kc1 = (64 + C4 * 16) ^ xk;      // kk=1 slice
    // region byte bases: A_b0=0, A_b1=32768, B_b0=65536, B_b1=98304
    const int aRB0 = 0     + wm_i * 16384 + fr * 128;
    const int aRB1 = 32768 + wm_i * 16384 + fr * 128;
    const int bRB0 = 65536 + (wn_i >> 1) * 16384 + (wn_i & 1) * 8192 + fr * 128;
    const int bRB1 = 98304 + (wn_i >> 1) * 16384 + (wn_i & 1) * 8192 + fr * 128;

    f32x4  acc[8][4] = {};
    bf16x8 a_[4][2], b0_[2][2], b1_[2][2];

    // prologue: A(0)->A_b0, B(0)->B_b0, B(1)->B_b1; drain; barrier
    STAGE(A, aso, 0,     0, 0); STAGE(A, aso, 0,     0, 1);
    STAGE(W, bso, 32768, 0, 0); STAGE(W, bso, 32768, 0, 1);
    STAGE(W, bso, 49152, 1, 0); STAGE(W, bso, 49152, 1, 1);
    VM0; BAR;

    const int NIT = K >> 7;          // 2 K-tiles (BK=64) per iteration
    for (int it = 0; it < NIT; ++it) {
        const int tA1 = 2 * it + 1;
        const int tN  = 2 * it + 2;
        const bool pf = (it + 1 < NIT);
        // p1: tile 2it quadrant (0,0)
        RD_A(aRB0, 0); RD_B(bRB0, 0, b0_);
        STAGE(A, aso, 16384, tA1, 0);
        BAR; PRIO1; MM(0, 0, b0_); PRIO0; BAR;
        // p2: (0,1)
        RD_B(bRB0, 1, b1_);
        STAGE(A, aso, 16384, tA1, 1);
        BAR; PRIO1; MM(0, 1, b1_); PRIO0; BAR;
        // p3: (1,0)
        RD_A(aRB0, 1);
        if (pf) STAGE(W, bso, 32768, tN, 0);
        BAR; PRIO1; MM(1, 0, b0_); PRIO0; BAR;
        // p4: (1,1)  [counted vmcnt; full drain on last iter]
        if (pf) { STAGE(W, bso, 32768, tN, 1); VM4; } else { VM0; }
        BAR; PRIO1; MM(1, 1, b1_); PRIO0; BAR;
        // p5: tile 2it+1 quadrant (0,0)
        RD_A(aRB1, 0); RD_B(bRB1, 0, b0_);
        if (pf) STAGE(A, aso, 0, tN, 0);
        BAR; PRIO1; MM(0, 0, b0_); PRIO0; BAR;
        // p6: (0,1)
        RD_B(bRB1, 1, b1_);
        if (pf) STAGE(A, aso, 0, tN, 1);
        BAR; PRIO1; MM(0, 1, b1_); PRIO0; BAR;
        // p7: (1,0)
        RD_A(aRB1, 1);
        if (pf) STAGE(W, bso, 49152, 2 * it + 3, 0);
        BAR; PRIO1; MM(1, 0, b0_); PRIO0; BAR;
        // p8: (1,1)
        if (pf) { STAGE(W, bso, 49152, 2 * it + 3, 1); VM4; }
        BAR; PRIO1; MM(1, 1, b1_); PRIO0; BAR;
    }

    // ---------- epilogue: repack through (dead) LDS, 16B stores ----------
    bf16* cs = (bf16*)lds;                      // 256x256 bf16 = 128KB
    #pragma unroll
    for (int i = 0; i < 8; ++i)
        #pragma unroll
        for (int j = 0; j < 4; ++j)
            #pragma unroll
            for (int r = 0; r < 4; ++r) {
                const int m = wm_i * 128 + i * 16 + C4 * 4 + r;
                const int n = wn_i * 64  + j * 16 + fr;
                cs[m * 256 + (n ^ ((m & 7) << 3))] = sto<bf16>(acc[i][j][r]);
            }
    __syncthreads();
    bf16* dst; int colb;
    if (n0 < split) { dst = out0; colb = n0; }
    else            { dst = out1; colb = n0 - split; }
    #pragma unroll
    for (int g = 0; g < 16; ++g) {
        const int G = tid + 512 * g;
        const int m = G >> 5;
        const int c = G & 31;
        const uint4 v = *(const uint4*)&cs[m * 256 + ((c * 8) ^ ((m & 7) << 3))];
        *(uint4*)&dst[(size_t)(m0 + m) * split + colb + c * 8] = v;
    }
}

// -------- MFMA GEMM: bf16 async-LDS dbuf staging + vectorized epilogue -----
// (kept for K3/K4/K6 — grids too small for 256^2 tiles)
template<typename TO, int SPLITK, int EPI>
__global__ __launch_bounds__(256)
void gemm_mfma(const bf16* __restrict__ A, const bf16* __restrict__ W,
               TO* __restrict__ out, TO* __restrict__ out2,
               const float* __restrict__ bias,
               int M, int N, int K, int split, int kchunk)
{
    __shared__ __align__(16) short smem[16384];   // 32 KB
    short* As = smem;            // [2][4096]
    short* Bs = smem + 8192;     // [2][4096]

    const int tid  = threadIdx.x;
    const int lane = tid & 63;
    const int wv   = tid >> 6;
    const int wm = (wv & 1) * 64;
    const int wn = (wv >> 1) * 64;
    const int m0 = blockIdx.y * 128;
    const int n0 = blockIdx.x * 128;

    const int p0 = wv * 64 + lane;
    const int p1 = p0 + 256;
    const int r0 = p0 >> 2, c0 = (p0 & 3) ^ ((r0 >> 1) & 3);
    const int r1 = p1 >> 2, c1 = (p1 & 3) ^ ((r1 >> 1) & 3);

    const bf16* srcA0 = A + (size_t)(m0 + r0) * K + c0 * 8;
    const bf16* srcA1 = A + (size_t)(m0 + r1) * K + c1 * 8;
    int nr0 = n0 + r0; if (nr0 >= N) nr0 = N - 1;
    int nr1 = n0 + r1; if (nr1 >= N) nr1 = N - 1;
    const bf16* srcB0 = W + (size_t)nr0 * K + c0 * 8;
    const bf16* srcB1 = W + (size_t)nr1 * K + c1 * 8;

    const int C4 = lane >> 4;
    const int fr = lane & 15;
    int aOff[4], bOff[4];
    #pragma unroll
    for (int i = 0; i < 4; ++i) {
        const int R = wm + i * 16 + fr;
        aOff[i] = R * 32 + ((C4 ^ ((R >> 1) & 3)) << 3);
    }
    #pragma unroll
    for (int j = 0; j < 4; ++j) {
        const int R = wn + j * 16 + fr;
        bOff[j] = R * 32 + ((C4 ^ ((R >> 1) & 3)) << 3);
    }

    f32x4 acc[4][4] = {};

    const int kb  = blockIdx.z * kchunk;
    const int nit = kchunk / 32;

    // prologue: stage tile 0 into buffer 0
    gll16(srcA0 + kb, &As[wv * 512]);
    gll16(srcA1 + kb, &As[(wv + 4) * 512]);
    gll16(srcB0 + kb, &Bs[wv * 512]);
    gll16(srcB1 + kb, &Bs[(wv + 4) * 512]);

    for (int it = 0; it < nit; ++it) {
        __syncthreads();                 // buf p ready; prior reads of buf q done
        const int p = it & 1;
        if (it + 1 < nit) {
            const int q  = p ^ 1;
            const int k1 = kb + (it + 1) * 32;
            gll16(srcA0 + k1, &As[q * 4096 + wv * 512]);
            gll16(srcA1 + k1, &As[q * 4096 + (wv + 4) * 512]);
            gll16(srcB0 + k1, &Bs[q * 4096 + wv * 512]);
            gll16(srcB1 + k1, &Bs[q * 4096 + (wv + 4) * 512]);
        }
        bf16x8 af[4], bfr[4];
        #pragma unroll
        for (int i = 0; i < 4; ++i) af[i]  = *(const bf16x8*)&As[p * 4096 + aOff[i]];
        #pragma unroll
        for (int j = 0; j < 4; ++j) bfr[j] = *(const bf16x8*)&Bs[p * 4096 + bOff[j]];
        #pragma unroll
        for (int i = 0; i < 4; ++i)
            #pragma unroll
            for (int j = 0; j < 4; ++j)
                acc[i][j] = __builtin_amdgcn_mfma_f32_16x16x32_bf16(af[i], bfr[j], acc[i][j], 0, 0, 0);
    }

    __syncthreads();   // all LDS reads done; smem free for epilogue repack

    const int rb = (lane >> 4) * 4;

    if constexpr (sizeof(TO) == 2) {
        // bf16 out: one pass, 128x128 bf16 = 32 KB
        bf16* cs = (bf16*)smem;
        #pragma unroll
        for (int i = 0; i < 4; ++i)
            #pragma unroll
            for (int j = 0; j < 4; ++j)
                #pragma unroll
                for (int r = 0; r < 4; ++r) {
                    const int m = wm + i * 16 + rb + r;
                    const int n = wn + j * 16 + fr;
                    float v = acc[i][j][r];
                    if (EPI == 1) {
                        v += bias[n0 + n];
                        // fast softplus via v_exp/v_log (bf16-out quantization
                        // dwarfs ~1ulp intrinsic error; libm was 42us, R1)
                        v = (v > 20.f) ? v : __logf(1.f + __expf(v));
                    }
                    const int key = (m >> 2) & 3;
                    cs[m * 128 + (n ^ ((key & 1) << 4) ^ ((key >> 1) << 5))] = sto<bf16>(v);
                }
        __syncthreads();
        TO* ob; int nc0; int ostr;
        if (split > 0) {
            if (n0 < split) { ob = out;  nc0 = n0;         }
            else            { ob = out2; nc0 = n0 - split; }
            ostr = split;
        } else { ob = out; nc0 = n0; ostr = N; }
        #pragma unroll
        for (int g8 = 0; g8 < 8; ++g8) {
            const int G = tid + 256 * g8;
            const int mrow = G >> 4;
            const int cg = G & 15;
            const int key = (mrow >> 2) & 3;
            const int nst = (cg * 8) ^ ((key & 1) << 4) ^ ((key >> 1) << 5);
            if (n0 + nst < N) {
                const uint4 val = *(const uint4*)&cs[mrow * 128 + cg * 8];
                *(uint4*)&ob[(size_t)(m0 + mrow) * ostr + nc0 + nst] = val;
            }
        }
    } else {
        // f32 out: two n-half passes of 128x64 f32 = 32 KB
        float* fs = (float*)smem;
        float* obase = SPLITK ? ((float*)out + (size_t)blockIdx.z * M * N) : (float*)out;
        #pragma unroll
        for (int ph = 0; ph < 2; ++ph) {
            __syncthreads();
            if ((wn >> 6) == ph) {       // the 2 waves owning this n-half write
                #pragma unroll
                for (int i = 0; i < 4; ++i)
                    #pragma unroll
                    for (int j = 0; j < 4; ++j)
                        #pragma unroll
                        for (int r = 0; r < 4; ++r) {
                            const int m = wm + i * 16 + rb + r;
                            const int qq = j * 16 + fr;
                            fs[m * 64 + (qq ^ (((m >> 2) & 1) << 4))] = acc[i][j][r];
                        }
            }
            __syncthreads();
            #pragma unroll
            for (int g8 = 0; g8 < 8; ++g8) {
                const int G = tid + 256 * g8;
                const int mrow = G >> 4;
                const int cg = G & 15;
                const int qst = (cg * 4) ^ (((mrow >> 2) & 1) << 4);
                const int n_g = 64 * ph + qst;
                if (n0 + n_g < N) {
                    const float4 val = *(const float4*)&fs[mrow * 64 + cg * 4];
                    *(float4*)&obase[(size_t)(m0 + mrow) * N + n0 + n_g] = val;
                }
            }
        }
    }
}

// sum 8 split-K partials of the bcx projection; emit xr (bf16, 4096x64)
// and B|C (f32, 4096x32).
__global__ __launch_bounds__(256)
void reduce_bcx(const float* __restrict__ P8, bf16* __restrict__ xr,
                float* __restrict__ BC)
{
    const int u = blockIdx.x * 256 + threadIdx.x;   // over MROWS*NBCX
    const int m = u / NBCX;
    const int n = u - m * NBCX;
    float s = 0.f;
    #pragma unroll
    for (int k = 0; k < 8; ++k) s += P8[(size_t)k * MROWS * NBCX + u];
    if (n < 64) xr[(size_t)m * 64 + n] = sto<bf16>(s);
    else        BC[(size_t)m * 32 + (n - 64)] = s;
}

// causal depthwise conv (d_conv=4) + bias + SiLU.
// Sliding-window: each thread produces 8 consecutive t's for its 8-d
// group from an 11-row register window (R7: 67 -> 23 MB reads, +12us win).
__global__ __launch_bounds__(256)
void conv_silu(const bf16* __restrict__ x_in, const float* __restrict__ cw,
               const float* __restrict__ cb, bf16* __restrict__ x_conv)
{
    const int tg = blockIdx.x;            // 512 t-groups of 8
    const int b  = tg >> 8;               // 256 groups per batch
    const int t0 = (tg & 255) << 3;
    const int d  = threadIdx.x * 8;
    const size_t rowbase = ((size_t)b * LSEQ + t0) * DINNER + d;

    uint4 v[11];
    const uint4 z4 = make_uint4(0, 0, 0, 0);
    #pragma unroll
    for (int r = 0; r < 11; ++r) {
        const int t = t0 + r - 3;
        v[r] = (t >= 0) ? *(const uint4*)(x_in + rowbase + (size_t)(r - 3) * DINNER) : z4;
    }
    float4 wq[8]; float bq[8];
    #pragma unroll
    for (int e = 0; e < 8; ++e) {
        wq[e] = *(const float4*)(cw + (size_t)(d + e) * 4);
        bq[e] = cb[d + e];
    }
    #pragma unroll
    for (int r = 0; r < 8; ++r) {
        const bf16* e0 = (const bf16*)&v[r];
        const bf16* e1 = (const bf16*)&v[r + 1];
        const bf16* e2 = (const bf16*)&v[r + 2];
        const bf16* e3 = (const bf16*)&v[r + 3];
        bf16 ob[8];
        #pragma unroll
        for (int e = 0; e < 8; ++e) {
            float a = bq[e];
            a = fmaf(wq[e].x, cvt(e0[e]), a);
            a = fmaf(wq[e].y, cvt(e1[e]), a);
            a = fmaf(wq[e].z, cvt(e2[e]), a);
            a = fmaf(wq[e].w, cvt(e3[e]), a);
            const float sig = 1.f / (1.f + __expf(-a));
            ob[e] = sto<bf16>(a * sig);
        }
        *(uint4*)(x_conv + rowbase + (size_t)r * DINNER) = *(const uint4*)ob;
    }
}

// ---------------- chunked two-phase selective scan ----------------
// B/C rows in BC buffer: row stride 32 f32, B at +0, C at +16.
// 1 d per thread (R5's 2-d/thread spilled h/P/Af state past the VGPR
// budget -> scratch thrash; TLP at 2048 waves hides the latency here).
__global__ __launch_bounds__(64)
void scan_phase_a(const bf16* __restrict__ x_conv, const bf16* __restrict__ dt,
                  const float* __restrict__ BC, const float* __restrict__ A_log,
                  float* __restrict__ hend, float* __restrict__ Pprod)
{
    const int lane = threadIdx.x;
    const int c = blockIdx.x;
    const int d = blockIdx.y * 64 + lane;
    const int b = blockIdx.z;

    float Af[DSTATE];
    #pragma unroll
    for (int s = 0; s < DSTATE; ++s) Af[s] = -__expf(A_log[d * DSTATE + s]);

    float h[DSTATE], P[DSTATE];
    #pragma unroll
    for (int s = 0; s < DSTATE; ++s) { h[s] = 0.f; P[s] = 1.f; }

    const size_t base = ((size_t)b * LSEQ + (size_t)c * CHUNK) * DINNER + d;
    const bf16* xp  = x_conv + base;
    const bf16* dtp = dt + base;
    const float* Bp = BC + ((size_t)b * LSEQ + (size_t)c * CHUNK) * 32;

    for (int t0 = 0; t0 < CHUNK; t0 += 4) {
        float xg[4], dtg[4];
        #pragma unroll
        for (int j = 0; j < 4; ++j) {
            xg[j]  = cvt(xp [(size_t)(t0 + j) * DINNER]);
            dtg[j] = cvt(dtp[(size_t)(t0 + j) * DINNER]);
        }
        #pragma unroll
        for (int j = 0; j < 4; ++j) {
            float Bv[DSTATE];
            const float* Br = Bp + (size_t)(t0 + j) * 32;
            *(float4*)(&Bv[0])  = *(const float4*)(Br + 0);
            *(float4*)(&Bv[4])  = *(const float4*)(Br + 4);
            *(float4*)(&Bv[8])  = *(const float4*)(Br + 8);
            *(float4*)(&Bv[12]) = *(const float4*)(Br + 12);
            const float dtv = dtg[j];
            const float dtx = dtv * xg[j];
            #pragma unroll
            for (int s = 0; s < DSTATE; ++s) {
                const float a = fmaf(dtv, Af[s], 1.0f);
                h[s] = fmaf(h[s], a, dtx * Bv[s]);
                P[s] *= a;
            }
        }
    }

    const size_t oidx = (((size_t)b * NCHUNK + c) * DINNER + d) * DSTATE;
    #pragma unroll
    for (int s = 0; s < DSTATE; ++s) {
        hend [oidx + s] = h[s];
        Pprod[oidx + s] = P[s];
    }
}

__global__ __launch_bounds__(256)
void scan_combine(float* __restrict__ hend, const float* __restrict__ Pprod)
{
    const int u = blockIdx.x * 256 + threadIdx.x;
    const int b = blockIdx.y;
    float h = 0.f;
    for (int c = 0; c < NCHUNK; ++c) {
        const size_t idx = ((size_t)b * NCHUNK + c) * DS_TOT + u;
        const float he = hend[idx];
        const float p  = Pprod[idx];
        hend[idx] = h;
        h = fmaf(p, h, he);
    }
}

__global__ __launch_bounds__(64)
void scan_phase_c(const bf16* __restrict__ x_conv, const bf16* __restrict__ dt,
                  const float* __restrict__ BC,
                  const float* __restrict__ A_log, const float* __restrict__ Dw,
                  const float* __restrict__ hin, bf16* __restrict__ zy)
{
    const int lane = threadIdx.x;
    const int c = blockIdx.x;
    const int d = blockIdx.y * 64 + lane;
    const int b = blockIdx.z;

    float Af[DSTATE];
    #pragma unroll
    for (int s = 0; s < DSTATE; ++s) Af[s] = -__expf(A_log[d * DSTATE + s]);
    const float Dv = Dw[d];

    float h[DSTATE];
    const size_t hidx = (((size_t)b * NCHUNK + c) * DINNER + d) * DSTATE;
    #pragma unroll
    for (int s = 0; s < DSTATE; ++s) h[s] = hin[hidx + s];

    const size_t base = ((size_t)b * LSEQ + (size_t)c * CHUNK) * DINNER + d;
    const bf16* xp  = x_conv + base;
    const bf16* dtp = dt + base;
    bf16*       zp  = zy + base;
    const float* Bp = BC + ((size_t)b * LSEQ + (size_t)c * CHUNK) * 32;
    const float* Cp = Bp + 16;

    for (int t0 = 0; t0 < CHUNK; t0 += 4) {
        float xg[4], dtg[4], zg[4];
        #pragma unroll
        for (int j = 0; j < 4; ++j) {
            xg[j]  = cvt(xp [(size_t)(t0 + j) * DINNER]);
            dtg[j] = cvt(dtp[(size_t)(t0 + j) * DINNER]);
            zg[j]  = cvt(zp [(size_t)(t0 + j) * DINNER]);
        }
        #pragma unroll
        for (int j = 0; j < 4; ++j) {
            float Bv[DSTATE], Cv[DSTATE];
            const float* Br = Bp + (size_t)(t0 + j) * 32;
            const float* Cr = Cp + (size_t)(t0 + j) * 32;
            *(float4*)(&Bv[0])  = *(const float4*)(Br + 0);
            *(float4*)(&Bv[4])  = *(const float4*)(Br + 4);
            *(float4*)(&Bv[8])  = *(const float4*)(Br + 8);
            *(float4*)(&Bv[12]) = *(const float4*)(Br + 12);
            *(float4*)(&Cv[0])  = *(const float4*)(Cr + 0);
            *(float4*)(&Cv[4])  = *(const float4*)(Cr + 4);
            *(float4*)(&Cv[8])  = *(const float4*)(Cr + 8);
            *(float4*)(&Cv[12]) = *(const float4*)(Cr + 12);
            const float dtv = dtg[j];
            const float dtx = dtv * xg[j];
            float y = 0.f;
            #pragma unroll
            for (int s = 0; s < DSTATE; ++s) {
                const float a = fmaf(dtv, Af[s], 1.0f);
                h[s] = fmaf(h[s], a, dtx * Bv[s]);
                y = fmaf(h[s], Cv[s], y);
            }
            const float zv = zg[j];
            const float sig = 1.f / (1.f + __expf(-zv));
            zp[(size_t)(t0 + j) * DINNER] = sto<bf16>(fmaf(Dv, xg[j], y) * (zv * sig));
        }
    }
}

extern "C" void kernel_launch(void* const* d_in, const int* in_sizes, int n_in,
                              void* d_out, int out_size, void* d_ws, size_t ws_size,
                              hipStream_t stream)
{
    const float* x          = (const float*)d_in[0];
    const float* in_proj_w  = (const float*)d_in[1];
    const float* conv_w     = (const float*)d_in[2];
    const float* conv_b     = (const float*)d_in[3];
    const float* A_log      = (const float*)d_in[4];
    const float* Dw         = (const float*)d_in[5];
    const float* dt_proj_w  = (const float*)d_in[6];
    const float* dt_proj_b  = (const float*)d_in[7];
    const float* x_proj_w   = (const float*)d_in[8];
    const float* B_proj_w   = (const float*)d_in[9];
    const float* C_proj_w   = (const float*)d_in[10];
    const float* out_proj_w = (const float*)d_in[11];
    float* out = (float*)d_out;

    // workspace (~93 MB, with aliasing) — identical to R9 layout
    const size_t MD = (size_t)MROWS * DINNER;
    bf16* buf0 = (bf16*)d_ws;                        // x_in -> P8 -> dt
    bf16* buf1 = buf0 + MD;                          // z -> y (in place)
    bf16* buf2 = buf1 + MD;                          // x_conv
    bf16* xbf  = buf2 + MD;                          // x bf16 (dead after K1)
    bf16* wbf1 = xbf  + (size_t)MROWS * DMODEL;      // in_proj bf16
    bf16* wbf2 = wbf1 + (size_t)2 * DINNER * DMODEL; // out_proj bf16
    bf16* wbc  = wbf2 + (size_t)DMODEL * DINNER;     // packed bcx weights bf16
    bf16* wdt  = wbc  + (size_t)NBCX * DINNER;       // dt_proj_w bf16
    float* hend = (float*)(wdt + (size_t)DINNER * DTRANK);
    float* Pp   = hend + (size_t)BSZ * NCHUNK * DS_TOT;
    // aliases over dead regions:
    bf16*  xr_bf = xbf;                              // 4096x64 bf16 (xbf dead after K1)
    float* BCbuf = (float*)(xbf + (size_t)MROWS * DTRANK); // 4096x32 f32
    float* P8 = (float*)buf0;  // 12.58 MB over buf0 (16.78): x_in dead after conv

    dim3 blk(256);
    const int na = MROWS * DMODEL;
    const int nb = 2 * DINNER * DMODEL;
    const int nc = DMODEL * DINNER;
    const int nd = DINNER * DTRANK;
    const int nbcx = NBCX * DINNER;

    // fused f32->bf16 converts + weight pack (8 elems/thread)
    cvt_all<<<(na + nb + nc + nd + nbcx) / 2048, blk, 0, stream>>>(
        x, in_proj_w, out_proj_w, dt_proj_w, x_proj_w, B_proj_w, C_proj_w,
        xbf, wbf1, wbf2, wdt, wbc, na, nb, nc, nd, nbcx);

    // K1: xz = x @ in_proj_w^T — 256^2 8-phase MFMA, split into x_in | z
    gemm256<<<dim3((MROWS / 256) * (2 * DINNER / 256)), dim3(512), 0, stream>>>(
        xbf, wbf1, buf0, buf1, 2 * DINNER, DMODEL, DINNER);

    // K2: causal depthwise conv + SiLU (sliding window, 8 t's/thread)
    conv_silu<<<MROWS / 8, blk, 0, stream>>>(buf0, conv_w, conv_b, buf2);

    // K3: fused xr|B|C projection, split-K=8, partials -> P8 (over dead x_in)
    gemm_mfma<float, 1, 0><<<dim3(1, MROWS / 128, 8), blk, 0, stream>>>(
        buf2, wbc, P8, (float*)nullptr, nullptr, MROWS, NBCX, DINNER, 0, DINNER / 8);

    // reduce partials -> xr (bf16) + B|C (f32)
    reduce_bcx<<<(MROWS * NBCX) / 256, blk, 0, stream>>>(P8, xr_bf, BCbuf);

    // K4: dt = softplus(xr @ dt_proj_w^T + b)  (MFMA, K=64) -> buf0 (over dead P8)
    gemm_mfma<bf16, 0, 1><<<dim3(DINNER / 128, MROWS / 128, 1), blk, 0, stream>>>(
        xr_bf, wdt, buf0, (bf16*)nullptr, dt_proj_b, MROWS, DINNER, DTRANK, 0, DTRANK);

    // K5: chunked two-phase selective scan (y over z in place in buf1)
    scan_phase_a<<<dim3(NCHUNK, DINNER / 64, BSZ), dim3(64), 0, stream>>>(
        buf2, buf0, BCbuf, A_log, hend, Pp);
    scan_combine<<<dim3(DS_TOT / 256, BSZ), dim3(256), 0, stream>>>(hend, Pp);
    scan_phase_c<<<dim3(NCHUNK, DINNER / 64, BSZ), dim3(64), 0, stream>>>(
        buf2, buf0, BCbuf, A_log, Dw, hend, buf1);

    // K6: out = y @ out_proj_w^T (MFMA dbuf) -> f32 d_out
    gemm_mfma<float, 0, 0><<<dim3(DMODEL / 128, MROWS / 128, 1), blk, 0, stream>>>(
        buf1, wbf2, out, (float*)nullptr, nullptr, MROWS, DMODEL, DINNER, 0, DINNER);
}